// Round 5
// baseline (489.449 us; speedup 1.0000x reference)
//
#include <hip/hip_runtime.h>
#include <cmath>
#include <complex>
#include <algorithm>

#ifndef M_PI
#define M_PI 3.14159265358979323846
#endif

// ---------------- coefficient structs (passed by value as kernel args) ---------
struct FiltArg {
  double b0[3], b1[3], b2[3], a1[3], a2[3];
  double zi0[3], zi1[3];
  double A32[36];              // (state-transition matrix)^32, 6x6 row-major
};
struct FirArg { float h[526]; };  // 25 leading zeros + 501-tap kaiser-sinc, *UP

// ---------------- host-side filter design (exact replica of reference) --------
static void design_sos(FiltArg& sa) {
  const int order = 6;
  const double wn = 0.5 / 50.0;
  const double fs = 2.0;
  double warped = 2.0 * fs * std::tan(M_PI * wn / fs);
  std::complex<double> p[6];
  for (int i = 0; i < order; i++) {
    int m = -order + 1 + 2 * i;                      // -5,-3,-1,1,3,5
    p[i] = -std::exp(std::complex<double>(0.0, M_PI * m / (2.0 * order)));
  }
  std::complex<double> prod1(1, 0);
  for (int i = 0; i < 6; i++) prod1 *= -p[i];
  double k = (1.0 / prod1).real();
  for (int i = 0; i < 6; i++) p[i] = warped / p[i];
  const double fs2 = 2.0 * fs;
  std::complex<double> num(1, 0), den(1, 0);
  for (int i = 0; i < 6; i++) { num *= fs2; den *= (fs2 - p[i]); }
  k *= (num / den).real();
  for (int i = 0; i < 6; i++) p[i] = (fs2 + p[i]) / (fs2 - p[i]);
  std::complex<double> pp[3]; int n = 0;
  for (int i = 0; i < 6; i++) if (p[i].imag() > 0) pp[n++] = p[i];
  std::stable_sort(pp, pp + 3,
    [](const std::complex<double>& A, const std::complex<double>& B) {
      return std::fabs(std::abs(A) - 1.0) > std::fabs(std::abs(B) - 1.0);
    });
  double sos[3][6];
  for (int s = 0; s < 3; s++) {
    double g = (s == 0) ? k : 1.0;
    sos[s][0] = g; sos[s][1] = -2.0 * g; sos[s][2] = g;
    sos[s][3] = 1.0; sos[s][4] = -2.0 * pp[s].real(); sos[s][5] = std::norm(pp[s]);
  }
  double scale = 1.0;
  for (int s = 0; s < 3; s++) {
    double b0 = sos[s][0], b1 = sos[s][1], b2 = sos[s][2];
    double a1 = sos[s][4], a2 = sos[s][5];
    double det = 1.0 + a1 + a2;                      // det of [[1+a1,-1],[a2,1]]
    double r0 = b1 - a1 * b0, r1 = b2 - a2 * b0;
    double z0 = (r0 + r1) / det;
    double z1 = ((1.0 + a1) * r1 - a2 * r0) / det;
    sa.b0[s] = b0; sa.b1[s] = b1; sa.b2[s] = b2; sa.a1[s] = a1; sa.a2[s] = a2;
    sa.zi0[s] = scale * z0; sa.zi1[s] = scale * z1;
    scale *= (b0 + b1 + b2) / (1.0 + a1 + a2);
  }
}

// one biquad-cascade step on a 6-dim state (host mirror of device step)
static double host_step(const FiltArg& c, double z[6], double v) {
  for (int s = 0; s < 3; s++) {
    double y = c.b0[s] * v + z[2 * s];
    z[2 * s]     = c.b1[s] * v - c.a1[s] * y + z[2 * s + 1];
    z[2 * s + 1] = c.b2[s] * v - c.a2[s] * y;
    v = y;
  }
  return v;
}

static void build_filt(FiltArg& c) {
  design_sos(c);
  double A[36];
  for (int j = 0; j < 6; j++) {
    double z[6] = {0, 0, 0, 0, 0, 0};
    z[j] = 1.0;
    host_step(c, z, 0.0);
    for (int i = 0; i < 6; i++) A[i * 6 + j] = z[i];
  }
  double M[36], T[36];
  for (int i = 0; i < 36; i++) M[i] = A[i];
  for (int sq = 0; sq < 5; sq++) {
    for (int i = 0; i < 6; i++)
      for (int j = 0; j < 6; j++) {
        double s = 0.0;
        for (int kk = 0; kk < 6; kk++) s += M[i * 6 + kk] * M[kk * 6 + j];
        T[i * 6 + j] = s;
      }
    for (int i = 0; i < 36; i++) M[i] = T[i];
  }
  for (int i = 0; i < 36; i++) c.A32[i] = M[i];
}

static double bessel_i0(double x) {
  double s = 1.0, t = 1.0;
  for (int k = 1; k < 64; k++) {
    double u = x / (2.0 * k);
    t *= u * u; s += t;
    if (t < 1e-18 * s) break;
  }
  return s;
}

static void design_fir(FirArg& fa) {
  double h[501];
  const double fc = 1.0 / 25.0;
  double denom = bessel_i0(5.0);
  double sum = 0.0;
  for (int nn = 0; nn < 501; nn++) {
    double m = nn - 250.0;
    double xx = fc * m;
    double snc = (nn == 250) ? 1.0 : std::sin(M_PI * xx) / (M_PI * xx);
    double r = (2.0 * nn) / 500.0 - 1.0;
    double w = bessel_i0(5.0 * std::sqrt(std::max(0.0, 1.0 - r * r))) / denom;
    h[nn] = fc * snc * w; sum += h[nn];
  }
  for (int nn = 0; nn < 25; nn++) fa.h[nn] = 0.0f;          // n_pre_pad = 25
  for (int nn = 0; nn < 501; nn++) fa.h[25 + nn] = (float)(h[nn] / sum * 16.0);
}

// ---------------- device helpers ----------------
__device__ inline double waveReduceSum(double v) {
  #pragma unroll
  for (int off = 32; off > 0; off >>= 1) v += __shfl_down(v, off, 64);
  return v;
}

// ---------------- kernel 1: channel select + demean over 10 channels ---------
__global__ __launch_bounds__(256) void k_chansel(const float* __restrict__ x,
                                                 float* __restrict__ xs) {
  int idx = blockIdx.x * 256 + threadIdx.x;
  if (idx >= 64 * 2000) return;
  int b = idx / 2000, t = idx % 2000;
  const int ch[10] = {126, 125, 48, 112, 67, 93, 10, 61, 39, 108};
  const float* xb = x + (size_t)b * 128 * 2000;
  float v[10]; float s = 0.f;
  #pragma unroll
  for (int c = 0; c < 10; c++) { v[c] = xb[ch[c] * 2000 + t]; s += v[c]; }
  s *= 0.1f;
  #pragma unroll
  for (int c = 0; c < 10; c++) xs[((size_t)b * 10 + c) * 2000 + t] = v[c] - s;
}

// ---------------- kernel 2: filtfilt via chunked linear-recurrence scan -------
__global__ __launch_bounds__(64) void k_filtfilt(float* __restrict__ xs, FiltArg c) {
  __shared__ double yf[2048];
  __shared__ double Fs[64][6];
  __shared__ double Zs[64][6];
  int r = blockIdx.x;
  int k = threadIdx.x;
  float* x = xs + (size_t)r * 2000;

  double b0[3], b1[3], b2[3], a1[3], a2[3];
  #pragma unroll
  for (int s = 0; s < 3; s++) {
    b0[s] = c.b0[s]; b1[s] = c.b1[s]; b2[s] = c.b2[s];
    a1[s] = c.a1[s]; a2[s] = c.a2[s];
  }
  auto step = [&](double* z, double v) -> double {
    #pragma unroll
    for (int s = 0; s < 3; s++) {
      double y = b0[s] * v + z[2 * s];
      z[2 * s]     = b1[s] * v - a1[s] * y + z[2 * s + 1];
      z[2 * s + 1] = b2[s] * v - a2[s] * y;
      v = y;
    }
    return v;
  };

  double xf0 = (double)x[0], xlast = (double)x[1999];
  auto ein = [&](int t) -> double {
    if (t < 21)   return 2.0 * xf0 - (double)x[21 - t];
    if (t < 2021) return (double)x[t - 21];
    if (t < 2042) return 2.0 * xlast - (double)x[4019 - t];
    return 0.0;
  };

  int t0 = k * 32;
  double z[6];

  #pragma unroll
  for (int i = 0; i < 6; i++) z[i] = 0.0;
  for (int i = 0; i < 32; i++) step(z, ein(t0 + i));
  #pragma unroll
  for (int i = 0; i < 6; i++) Fs[k][i] = z[i];
  __syncthreads();
  if (k == 0) {
    double zz[6];
    double e0 = 2.0 * xf0 - (double)x[21];
    #pragma unroll
    for (int s = 0; s < 3; s++) { zz[2 * s] = c.zi0[s] * e0; zz[2 * s + 1] = c.zi1[s] * e0; }
    for (int kk = 0; kk < 64; kk++) {
      #pragma unroll
      for (int i = 0; i < 6; i++) Zs[kk][i] = zz[i];
      double nz[6];
      #pragma unroll
      for (int i = 0; i < 6; i++) {
        double s = Fs[kk][i];
        #pragma unroll
        for (int j = 0; j < 6; j++) s += c.A32[i * 6 + j] * zz[j];
        nz[i] = s;
      }
      #pragma unroll
      for (int i = 0; i < 6; i++) zz[i] = nz[i];
    }
  }
  __syncthreads();
  #pragma unroll
  for (int i = 0; i < 6; i++) z[i] = Zs[k][i];
  for (int i = 0; i < 32; i++) yf[t0 + i] = step(z, ein(t0 + i));
  __syncthreads();

  auto rin = [&](int j) -> double { return (j <= 2041) ? yf[2041 - j] : 0.0; };
  #pragma unroll
  for (int i = 0; i < 6; i++) z[i] = 0.0;
  for (int i = 0; i < 32; i++) step(z, rin(t0 + i));
  #pragma unroll
  for (int i = 0; i < 6; i++) Fs[k][i] = z[i];
  __syncthreads();
  if (k == 0) {
    double zz[6];
    double yl = yf[2041];
    #pragma unroll
    for (int s = 0; s < 3; s++) { zz[2 * s] = c.zi0[s] * yl; zz[2 * s + 1] = c.zi1[s] * yl; }
    for (int kk = 0; kk < 64; kk++) {
      #pragma unroll
      for (int i = 0; i < 6; i++) Zs[kk][i] = zz[i];
      double nz[6];
      #pragma unroll
      for (int i = 0; i < 6; i++) {
        double s = Fs[kk][i];
        #pragma unroll
        for (int j = 0; j < 6; j++) s += c.A32[i * 6 + j] * zz[j];
        nz[i] = s;
      }
      #pragma unroll
      for (int i = 0; i < 6; i++) zz[i] = nz[i];
    }
  }
  __syncthreads();
  #pragma unroll
  for (int i = 0; i < 6; i++) z[i] = Zs[k][i];
  for (int i = 0; i < 32; i++) {
    double y = step(z, rin(t0 + i));
    int j = t0 + i;
    if (j >= 21 && j <= 2020) x[2020 - j] = (float)y;
  }
}

// ---------------- kernel 3: PE table (f64 trig) -------------------------------
__global__ __launch_bounds__(256) void k_pe(float* __restrict__ pe) {
  int i = blockIdx.x * 256 + threadIdx.x;
  if (i >= 1280 * 16) return;
  int t = i >> 4, d = i & 15, j = d >> 1;
  double div = exp(-((double)(2 * j)) * log(10000.0) / 16.0);
  double a = (double)t * div;
  pe[i] = (float)((d & 1) ? cos(a) : sin(a));
}

// ---------------- kernel 4: polyphase resample + tanh + per-row normalize ----
// f32 FIR accumulate + tanhf (err ~1e-5 << 1e-3 threshold); block stats in f64.
__global__ __launch_bounds__(256) void k_resample_norm(const float* __restrict__ xf,
                                                       float* __restrict__ xn,
                                                       FirArg fa) {
  int r = blockIdx.x;                         // 640 rows
  const float* x = xf + (size_t)r * 2000;
  float vals[5];
  #pragma unroll
  for (int kk = 0; kk < 5; kk++) {
    int o = threadIdx.x + kk * 256;           // 1280 outputs per row
    int P = 25 * (o + 11);
    int phase = P & 15;
    float acc = 0.f;
    for (int m = phase; m <= 525; m += 16) {
      int idx = (P - m) >> 4;
      if (idx >= 0 && idx < 2000) acc += fa.h[m] * x[idx];
    }
    vals[kk] = tanhf(acc);
  }
  double s = 0.0, ss = 0.0;
  #pragma unroll
  for (int kk = 0; kk < 5; kk++) {
    s += (double)vals[kk]; ss += (double)vals[kk] * (double)vals[kk];
  }
  s = waveReduceSum(s); ss = waveReduceSum(ss);
  __shared__ double red[8];
  int wid = threadIdx.x >> 6, lane = threadIdx.x & 63;
  if (lane == 0) { red[wid] = s; red[4 + wid] = ss; }
  __syncthreads();
  double S = red[0] + red[1] + red[2] + red[3];
  double SS = red[4] + red[5] + red[6] + red[7];
  double mean = S / 1280.0;
  double var = (SS - 1280.0 * mean * mean) / 1279.0;
  double sd = fmax(sqrt(fmax(var, 0.0)), 1e-6);
  float fmean = (float)mean, finv = (float)(1.0 / sd);
  #pragma unroll
  for (int kk = 0; kk < 5; kk++)
    xn[(size_t)r * 1280 + threadIdx.x + kk * 256] = (vals[kk] - fmean) * finv;
}

// ---------------- kernel 5: conv1d(10->16,k3) + relu + LN + PE ----------------
__global__ __launch_bounds__(256) void k_conv_ln_pe(const float* __restrict__ xn,
    const float* __restrict__ cw, const float* __restrict__ cb,
    const float* __restrict__ g0, const float* __restrict__ bt0,
    const float* __restrict__ pe, float* __restrict__ x0) {
  __shared__ float w[480], bias[16], gg[16], gb[16];
  for (int i = threadIdx.x; i < 480; i += 256) w[i] = cw[i];
  if (threadIdx.x < 16) {
    bias[threadIdx.x] = cb[threadIdx.x];
    gg[threadIdx.x] = g0[threadIdx.x];
    gb[threadIdx.x] = bt0[threadIdx.x];
  }
  __syncthreads();
  int idx = blockIdx.x * 256 + threadIdx.x;
  if (idx >= 64 * 1280) return;
  int b = idx / 1280, t = idx % 1280;
  const float* xb = xn + (size_t)b * 10 * 1280;
  float in[10][3];
  #pragma unroll
  for (int i = 0; i < 10; i++)
    #pragma unroll
    for (int k = 0; k < 3; k++) {
      int tt = t - 1 + k;
      in[i][k] = (tt >= 0 && tt < 1280) ? xb[i * 1280 + tt] : 0.f;
    }
  float o[16];
  #pragma unroll
  for (int oc = 0; oc < 16; oc++) {
    float a = bias[oc];
    #pragma unroll
    for (int i = 0; i < 10; i++)
      #pragma unroll
      for (int k = 0; k < 3; k++) a += in[i][k] * w[oc * 30 + i * 3 + k];
    o[oc] = fmaxf(a, 0.f);
  }
  float mu = 0.f;
  #pragma unroll
  for (int d = 0; d < 16; d++) mu += o[d];
  mu *= (1.f / 16.f);
  float var = 0.f;
  #pragma unroll
  for (int d = 0; d < 16; d++) { float dd = o[d] - mu; var += dd * dd; }
  var *= (1.f / 16.f);
  float inv = 1.f / sqrtf(var + 1e-5f);
  float* outp = x0 + (size_t)idx * 16;
  #pragma unroll
  for (int d = 0; d < 16; d++)
    outp[d] = (o[d] - mu) * inv * gg[d] + gb[d] + pe[t * 16 + d];
}

// ---------------- kernel 6: QKV projection -----------------------------------
__global__ __launch_bounds__(256) void k_qkv(const float* __restrict__ x0,
    const float* __restrict__ wqkv, const float* __restrict__ bqkv,
    float* __restrict__ Q, float* __restrict__ K, float* __restrict__ V) {
  __shared__ float w[768], bias[48];
  for (int i = threadIdx.x; i < 768; i += 256) w[i] = wqkv[i];
  if (threadIdx.x < 48) bias[threadIdx.x] = bqkv[threadIdx.x];
  __syncthreads();
  int idx = blockIdx.x * 256 + threadIdx.x;
  if (idx >= 64 * 1280) return;
  float xv[16];
  const float* xp = x0 + (size_t)idx * 16;
  #pragma unroll
  for (int d = 0; d < 16; d++) xv[d] = xp[d];
  float* qp = Q + (size_t)idx * 16;
  float* kp = K + (size_t)idx * 16;
  float* vp = V + (size_t)idx * 16;
  #pragma unroll
  for (int j = 0; j < 16; j++) {
    float a = bias[j];
    #pragma unroll
    for (int d = 0; d < 16; d++) a += xv[d] * w[j * 16 + d];
    qp[j] = a;
  }
  #pragma unroll
  for (int j = 0; j < 16; j++) {
    float a = bias[16 + j];
    #pragma unroll
    for (int d = 0; d < 16; d++) a += xv[d] * w[(16 + j) * 16 + d];
    kp[j] = a;
  }
  #pragma unroll
  for (int j = 0; j < 16; j++) {
    float a = bias[32 + j];
    #pragma unroll
    for (int d = 0; d < 16; d++) a += xv[d] * w[(32 + j) * 16 + d];
    vp[j] = a;
  }
}

// ---------------- kernel 7a: attention core (4 rows/thread, 8-way key split) --
// Block: 256 threads = 32 row-groups x 8 subs -> 128 q-rows/block, 640 blocks.
// Each thread: 4 q-rows, 160 keys (10 tiles x 16). K/V in LDS, row stride 20
// floats (16B-aligned). LDS b128 per (row,key) = 2 (was 4 at R=2) -> LDS issue
// ~64us, now balanced with the ~45us VALU floor. Sub-partials merged by
// __shfl_xor over the 3 low lane bits -- no atomics.
// Fixed-shift softmax: p = exp(0.25*s - SHIFT); scores sd~3.2, |s|max~18 so
// SHIFT=12 is overflow-safe and underflow-irrelevant.
#define ATT_SHIFT 12.0f
__global__ __launch_bounds__(256) void k_attn_core(const float* __restrict__ Q,
    const float* __restrict__ K, const float* __restrict__ V,
    float* __restrict__ A) {
  __shared__ float Ks[128 * 20], Vs[128 * 20];
  int tid = threadIdx.x;
  int b  = blockIdx.x / 10;
  int rg = blockIdx.x % 10;                 // row-group of 128 rows
  int grp = tid >> 3;                       // 0..31 : which 4-row group
  int sub = tid & 7;                        // 0..7  : key split
  int row0 = rg * 128 + grp * 4;
  size_t base = (size_t)b * 1280;

  float q[4][16];
  {
    const float4* qp = (const float4*)(Q + (base + row0) * 16);
    #pragma unroll
    for (int r = 0; r < 4; r++)
      #pragma unroll
      for (int c = 0; c < 4; c++)
        *(float4*)&q[r][c * 4] = qp[r * 4 + c];
  }

  float l[4] = {};
  float acc[4][16] = {};
  for (int t0 = 0; t0 < 1280; t0 += 128) {
    __syncthreads();
    const float4* kp = (const float4*)(K + (base + t0) * 16);
    const float4* vp = (const float4*)(V + (base + t0) * 16);
    for (int i = tid; i < 512; i += 256) {
      int rr = i >> 2, cc = i & 3;
      *(float4*)&Ks[rr * 20 + cc * 4] = kp[i];
      *(float4*)&Vs[rr * 20 + cc * 4] = vp[i];
    }
    __syncthreads();
    for (int j = 0; j < 16; j++) {
      int key = j * 8 + sub;
      float kv[16];
      #pragma unroll
      for (int c = 0; c < 4; c++)
        *(float4*)&kv[c * 4] = *(const float4*)&Ks[key * 20 + c * 4];
      float p[4];
      #pragma unroll
      for (int r = 0; r < 4; r++) {
        float s = 0.f;
        #pragma unroll
        for (int d = 0; d < 16; d++) s += q[r][d] * kv[d];
        p[r] = __expf(fmaf(s, 0.25f, -ATT_SHIFT));
        l[r] += p[r];
      }
      float vv[16];
      #pragma unroll
      for (int c = 0; c < 4; c++)
        *(float4*)&vv[c * 4] = *(const float4*)&Vs[key * 20 + c * 4];
      #pragma unroll
      for (int r = 0; r < 4; r++)
        #pragma unroll
        for (int d = 0; d < 16; d++) acc[r][d] += p[r] * vv[d];
    }
  }
  // merge the 8 sub-partials (lanes differing in bits 0..2 of the lane id)
  #pragma unroll
  for (int off = 1; off < 8; off <<= 1) {
    #pragma unroll
    for (int r = 0; r < 4; r++) {
      l[r] += __shfl_xor(l[r], off, 64);
      #pragma unroll
      for (int d = 0; d < 16; d++) acc[r][d] += __shfl_xor(acc[r][d], off, 64);
    }
  }
  if (sub == 0) {
    #pragma unroll
    for (int r = 0; r < 4; r++) {
      float rl = 1.f / l[r];
      float* ap = A + (base + row0 + r) * 16;
      #pragma unroll
      for (int d = 0; d < 16; d++) ap[d] = acc[r][d] * rl;
    }
  }
}

// ---------------- kernel 7b: combine + wo + LN1 + FFN + LN2 ------------------
__global__ __launch_bounds__(256) void k_attn_combine(
    const float* __restrict__ A, const float* __restrict__ x0,
    const float* __restrict__ wo, const float* __restrict__ bo,
    const float* __restrict__ w1, const float* __restrict__ b1,
    const float* __restrict__ w2, const float* __restrict__ b2,
    const float* __restrict__ g1, const float* __restrict__ bb1,
    const float* __restrict__ g2, const float* __restrict__ bb2,
    float* __restrict__ x2) {
  __shared__ float swo[256], sw1[512], sw2[512];
  __shared__ float sbo[16], sb1[32], sb2[16], sg1[16], sbb1[16], sg2[16], sbb2[16];
  int tid = threadIdx.x;
  swo[tid] = wo[tid];
  for (int i = tid; i < 512; i += 256) { sw1[i] = w1[i]; sw2[i] = w2[i]; }
  if (tid < 16) {
    sbo[tid] = bo[tid]; sb2[tid] = b2[tid];
    sg1[tid] = g1[tid]; sbb1[tid] = bb1[tid];
    sg2[tid] = g2[tid]; sbb2[tid] = bb2[tid];
  }
  if (tid < 32) sb1[tid] = b1[tid];
  __syncthreads();

  int idx = blockIdx.x * 256 + tid;          // [0, 81920)
  const float* pa = A + (size_t)idx * 16;
  float a[16];
  #pragma unroll
  for (int d = 0; d < 16; d++) a[d] = pa[d];
  // wo projection + residual
  float h[16];
  const float* xr = x0 + (size_t)idx * 16;
  #pragma unroll
  for (int d = 0; d < 16; d++) {
    float o = sbo[d];
    #pragma unroll
    for (int e = 0; e < 16; e++) o += a[e] * swo[d * 16 + e];
    h[d] = xr[d] + o;
  }
  // LN1
  float mu = 0.f;
  #pragma unroll
  for (int d = 0; d < 16; d++) mu += h[d];
  mu *= (1.f / 16.f);
  float var = 0.f;
  #pragma unroll
  for (int d = 0; d < 16; d++) { float dd = h[d] - mu; var += dd * dd; }
  var *= (1.f / 16.f);
  float inv = 1.f / sqrtf(var + 1e-5f);
  float x1[16];
  #pragma unroll
  for (int d = 0; d < 16; d++) x1[d] = (h[d] - mu) * inv * sg1[d] + sbb1[d];
  // FFN
  float t1[32];
  #pragma unroll
  for (int j = 0; j < 32; j++) {
    float u = sb1[j];
    #pragma unroll
    for (int d = 0; d < 16; d++) u += x1[d] * sw1[j * 16 + d];
    t1[j] = fmaxf(u, 0.f);
  }
  float h2[16];
  #pragma unroll
  for (int d = 0; d < 16; d++) {
    float u = sb2[d];
    #pragma unroll
    for (int j = 0; j < 32; j++) u += t1[j] * sw2[d * 32 + j];
    h2[d] = x1[d] + u;
  }
  // LN2
  mu = 0.f;
  #pragma unroll
  for (int d = 0; d < 16; d++) mu += h2[d];
  mu *= (1.f / 16.f);
  var = 0.f;
  #pragma unroll
  for (int d = 0; d < 16; d++) { float dd = h2[d] - mu; var += dd * dd; }
  var *= (1.f / 16.f);
  inv = 1.f / sqrtf(var + 1e-5f);
  float* outp = x2 + (size_t)idx * 16;
  #pragma unroll
  for (int d = 0; d < 16; d++) outp[d] = (h2[d] - mu) * inv * sg2[d] + sbb2[d];
}

// ---------------- kernel 8: mean-pool + fc -----------------------------------
__global__ __launch_bounds__(256) void k_pool(const float* __restrict__ x2,
    const float* __restrict__ wfc, const float* __restrict__ bfc,
    float* __restrict__ out) {
  int b = blockIdx.x;
  const float* xp = x2 + (size_t)b * 1280 * 16;
  float wv = wfc[threadIdx.x & 15];
  double part = 0.0;
  for (int i = threadIdx.x; i < 1280 * 16; i += 256)
    part += (double)xp[i] * (double)wv;
  part = waveReduceSum(part);
  __shared__ double red[4];
  int wid = threadIdx.x >> 6, lane = threadIdx.x & 63;
  if (lane == 0) red[wid] = part;
  __syncthreads();
  if (threadIdx.x == 0) {
    double S = red[0] + red[1] + red[2] + red[3];
    out[b] = (float)(S / 1280.0 + (double)bfc[0]);
  }
}

// ---------------- launch ------------------------------------------------------
extern "C" void kernel_launch(void* const* d_in, const int* in_sizes, int n_in,
                              void* d_out, int out_size, void* d_ws, size_t ws_size,
                              hipStream_t stream) {
  const float* x    = (const float*)d_in[0];
  const float* cw   = (const float*)d_in[1];
  const float* cb   = (const float*)d_in[2];
  const float* g0   = (const float*)d_in[3];
  const float* bt0  = (const float*)d_in[4];
  const float* wqkv = (const float*)d_in[5];
  const float* bqkv = (const float*)d_in[6];
  const float* wo   = (const float*)d_in[7];
  const float* bo   = (const float*)d_in[8];
  const float* w1   = (const float*)d_in[9];
  const float* b1   = (const float*)d_in[10];
  const float* w2   = (const float*)d_in[11];
  const float* b2   = (const float*)d_in[12];
  const float* g1   = (const float*)d_in[13];
  const float* bb1  = (const float*)d_in[14];
  const float* g2   = (const float*)d_in[15];
  const float* bb2  = (const float*)d_in[16];
  const float* wfc  = (const float*)d_in[17];
  const float* bfc  = (const float*)d_in[18];
  float* out = (float*)d_out;

  float* ws = (float*)d_ws;
  float* xs = ws;                       // 640*2000 = 1,280,000 (filtered in-place;
                                        // dead after k_resample_norm -> reused as A)
  float* y1 = xs + 1280000;             // 640*2042 = 1,306,880 (dead; layout spacer)
  float* xn = y1 + 1306880;             // 640*1280   =   819,200
  float* x0 = xn + 819200;              // 64*1280*16 = 1,310,720
  float* Q  = x0 + 1310720;
  float* Kb = Q  + 1310720;
  float* Vb = Kb + 1310720;
  float* x2 = Vb + 1310720;
  float* pe = x2 + 1310720;             // 1280*16 = 20,480   (total ~40 MB)

  // attention output buffer carved from the dead xs/y1 region
  float* A = ws;

  FiltArg fc; FirArg fa;
  build_filt(fc);
  design_fir(fa);

  k_chansel<<<(64 * 2000 + 255) / 256, 256, 0, stream>>>(x, xs);
  k_filtfilt<<<640, 64, 0, stream>>>(xs, fc);           // filtered written into xs
  k_pe<<<(1280 * 16 + 255) / 256, 256, 0, stream>>>(pe);
  k_resample_norm<<<640, 256, 0, stream>>>(xs, xn, fa); // last reader of xs
  k_conv_ln_pe<<<320, 256, 0, stream>>>(xn, cw, cb, g0, bt0, pe, x0);
  k_qkv<<<320, 256, 0, stream>>>(x0, wqkv, bqkv, Q, Kb, Vb);
  k_attn_core<<<640, 256, 0, stream>>>(Q, Kb, Vb, A);
  k_attn_combine<<<320, 256, 0, stream>>>(A, x0, wo, bo, w1, b1, w2, b2,
                                          g1, bb1, g2, bb2, x2);
  k_pool<<<64, 256, 0, stream>>>(x2, wfc, bfc, out);
}

// Round 6
// 312.746 us; speedup vs baseline: 1.5650x; 1.5650x over previous
//
#include <hip/hip_runtime.h>
#include <cmath>
#include <complex>
#include <algorithm>

#ifndef M_PI
#define M_PI 3.14159265358979323846
#endif

typedef _Float16 f16x8 __attribute__((ext_vector_type(8)));
typedef _Float16 f16x4 __attribute__((ext_vector_type(4)));
typedef float f32x4 __attribute__((ext_vector_type(4)));

// ---------------- coefficient structs (passed by value as kernel args) ---------
struct FiltArg {
  double b0[3], b1[3], b2[3], a1[3], a2[3];
  double zi0[3], zi1[3];
  double A32[36];              // (state-transition matrix)^32, 6x6 row-major
};
struct FirArg { float h[526]; };  // 25 leading zeros + 501-tap kaiser-sinc, *UP

// ---------------- host-side filter design (exact replica of reference) --------
static void design_sos(FiltArg& sa) {
  const int order = 6;
  const double wn = 0.5 / 50.0;
  const double fs = 2.0;
  double warped = 2.0 * fs * std::tan(M_PI * wn / fs);
  std::complex<double> p[6];
  for (int i = 0; i < order; i++) {
    int m = -order + 1 + 2 * i;                      // -5,-3,-1,1,3,5
    p[i] = -std::exp(std::complex<double>(0.0, M_PI * m / (2.0 * order)));
  }
  std::complex<double> prod1(1, 0);
  for (int i = 0; i < 6; i++) prod1 *= -p[i];
  double k = (1.0 / prod1).real();
  for (int i = 0; i < 6; i++) p[i] = warped / p[i];
  const double fs2 = 2.0 * fs;
  std::complex<double> num(1, 0), den(1, 0);
  for (int i = 0; i < 6; i++) { num *= fs2; den *= (fs2 - p[i]); }
  k *= (num / den).real();
  for (int i = 0; i < 6; i++) p[i] = (fs2 + p[i]) / (fs2 - p[i]);
  std::complex<double> pp[3]; int n = 0;
  for (int i = 0; i < 6; i++) if (p[i].imag() > 0) pp[n++] = p[i];
  std::stable_sort(pp, pp + 3,
    [](const std::complex<double>& A, const std::complex<double>& B) {
      return std::fabs(std::abs(A) - 1.0) > std::fabs(std::abs(B) - 1.0);
    });
  double sos[3][6];
  for (int s = 0; s < 3; s++) {
    double g = (s == 0) ? k : 1.0;
    sos[s][0] = g; sos[s][1] = -2.0 * g; sos[s][2] = g;
    sos[s][3] = 1.0; sos[s][4] = -2.0 * pp[s].real(); sos[s][5] = std::norm(pp[s]);
  }
  double scale = 1.0;
  for (int s = 0; s < 3; s++) {
    double b0 = sos[s][0], b1 = sos[s][1], b2 = sos[s][2];
    double a1 = sos[s][4], a2 = sos[s][5];
    double det = 1.0 + a1 + a2;                      // det of [[1+a1,-1],[a2,1]]
    double r0 = b1 - a1 * b0, r1 = b2 - a2 * b0;
    double z0 = (r0 + r1) / det;
    double z1 = ((1.0 + a1) * r1 - a2 * r0) / det;
    sa.b0[s] = b0; sa.b1[s] = b1; sa.b2[s] = b2; sa.a1[s] = a1; sa.a2[s] = a2;
    sa.zi0[s] = scale * z0; sa.zi1[s] = scale * z1;
    scale *= (b0 + b1 + b2) / (1.0 + a1 + a2);
  }
}

static double host_step(const FiltArg& c, double z[6], double v) {
  for (int s = 0; s < 3; s++) {
    double y = c.b0[s] * v + z[2 * s];
    z[2 * s]     = c.b1[s] * v - c.a1[s] * y + z[2 * s + 1];
    z[2 * s + 1] = c.b2[s] * v - c.a2[s] * y;
    v = y;
  }
  return v;
}

static void build_filt(FiltArg& c) {
  design_sos(c);
  double A[36];
  for (int j = 0; j < 6; j++) {
    double z[6] = {0, 0, 0, 0, 0, 0};
    z[j] = 1.0;
    host_step(c, z, 0.0);
    for (int i = 0; i < 6; i++) A[i * 6 + j] = z[i];
  }
  double M[36], T[36];
  for (int i = 0; i < 36; i++) M[i] = A[i];
  for (int sq = 0; sq < 5; sq++) {
    for (int i = 0; i < 6; i++)
      for (int j = 0; j < 6; j++) {
        double s = 0.0;
        for (int kk = 0; kk < 6; kk++) s += M[i * 6 + kk] * M[kk * 6 + j];
        T[i * 6 + j] = s;
      }
    for (int i = 0; i < 36; i++) M[i] = T[i];
  }
  for (int i = 0; i < 36; i++) c.A32[i] = M[i];
}

static double bessel_i0(double x) {
  double s = 1.0, t = 1.0;
  for (int k = 1; k < 64; k++) {
    double u = x / (2.0 * k);
    t *= u * u; s += t;
    if (t < 1e-18 * s) break;
  }
  return s;
}

static void design_fir(FirArg& fa) {
  double h[501];
  const double fc = 1.0 / 25.0;
  double denom = bessel_i0(5.0);
  double sum = 0.0;
  for (int nn = 0; nn < 501; nn++) {
    double m = nn - 250.0;
    double xx = fc * m;
    double snc = (nn == 250) ? 1.0 : std::sin(M_PI * xx) / (M_PI * xx);
    double r = (2.0 * nn) / 500.0 - 1.0;
    double w = bessel_i0(5.0 * std::sqrt(std::max(0.0, 1.0 - r * r))) / denom;
    h[nn] = fc * snc * w; sum += h[nn];
  }
  for (int nn = 0; nn < 25; nn++) fa.h[nn] = 0.0f;          // n_pre_pad = 25
  for (int nn = 0; nn < 501; nn++) fa.h[25 + nn] = (float)(h[nn] / sum * 16.0);
}

// ---------------- device helpers ----------------
__device__ inline double waveReduceSum(double v) {
  #pragma unroll
  for (int off = 32; off > 0; off >>= 1) v += __shfl_down(v, off, 64);
  return v;
}

// ---------------- kernel 1: channel select + demean over 10 channels ---------
__global__ __launch_bounds__(256) void k_chansel(const float* __restrict__ x,
                                                 float* __restrict__ xs) {
  int idx = blockIdx.x * 256 + threadIdx.x;
  if (idx >= 64 * 2000) return;
  int b = idx / 2000, t = idx % 2000;
  const int ch[10] = {126, 125, 48, 112, 67, 93, 10, 61, 39, 108};
  const float* xb = x + (size_t)b * 128 * 2000;
  float v[10]; float s = 0.f;
  #pragma unroll
  for (int c = 0; c < 10; c++) { v[c] = xb[ch[c] * 2000 + t]; s += v[c]; }
  s *= 0.1f;
  #pragma unroll
  for (int c = 0; c < 10; c++) xs[((size_t)b * 10 + c) * 2000 + t] = v[c] - s;
}

// ---------------- kernel 2: filtfilt via chunked linear-recurrence scan -------
__global__ __launch_bounds__(64) void k_filtfilt(float* __restrict__ xs, FiltArg c) {
  __shared__ double yf[2048];
  __shared__ double Fs[64][6];
  __shared__ double Zs[64][6];
  int r = blockIdx.x;
  int k = threadIdx.x;
  float* x = xs + (size_t)r * 2000;

  double b0[3], b1[3], b2[3], a1[3], a2[3];
  #pragma unroll
  for (int s = 0; s < 3; s++) {
    b0[s] = c.b0[s]; b1[s] = c.b1[s]; b2[s] = c.b2[s];
    a1[s] = c.a1[s]; a2[s] = c.a2[s];
  }
  auto step = [&](double* z, double v) -> double {
    #pragma unroll
    for (int s = 0; s < 3; s++) {
      double y = b0[s] * v + z[2 * s];
      z[2 * s]     = b1[s] * v - a1[s] * y + z[2 * s + 1];
      z[2 * s + 1] = b2[s] * v - a2[s] * y;
      v = y;
    }
    return v;
  };

  double xf0 = (double)x[0], xlast = (double)x[1999];
  auto ein = [&](int t) -> double {
    if (t < 21)   return 2.0 * xf0 - (double)x[21 - t];
    if (t < 2021) return (double)x[t - 21];
    if (t < 2042) return 2.0 * xlast - (double)x[4019 - t];
    return 0.0;
  };

  int t0 = k * 32;
  double z[6];

  #pragma unroll
  for (int i = 0; i < 6; i++) z[i] = 0.0;
  for (int i = 0; i < 32; i++) step(z, ein(t0 + i));
  #pragma unroll
  for (int i = 0; i < 6; i++) Fs[k][i] = z[i];
  __syncthreads();
  if (k == 0) {
    double zz[6];
    double e0 = 2.0 * xf0 - (double)x[21];
    #pragma unroll
    for (int s = 0; s < 3; s++) { zz[2 * s] = c.zi0[s] * e0; zz[2 * s + 1] = c.zi1[s] * e0; }
    for (int kk = 0; kk < 64; kk++) {
      #pragma unroll
      for (int i = 0; i < 6; i++) Zs[kk][i] = zz[i];
      double nz[6];
      #pragma unroll
      for (int i = 0; i < 6; i++) {
        double s = Fs[kk][i];
        #pragma unroll
        for (int j = 0; j < 6; j++) s += c.A32[i * 6 + j] * zz[j];
        nz[i] = s;
      }
      #pragma unroll
      for (int i = 0; i < 6; i++) zz[i] = nz[i];
    }
  }
  __syncthreads();
  #pragma unroll
  for (int i = 0; i < 6; i++) z[i] = Zs[k][i];
  for (int i = 0; i < 32; i++) yf[t0 + i] = step(z, ein(t0 + i));
  __syncthreads();

  auto rin = [&](int j) -> double { return (j <= 2041) ? yf[2041 - j] : 0.0; };
  #pragma unroll
  for (int i = 0; i < 6; i++) z[i] = 0.0;
  for (int i = 0; i < 32; i++) step(z, rin(t0 + i));
  #pragma unroll
  for (int i = 0; i < 6; i++) Fs[k][i] = z[i];
  __syncthreads();
  if (k == 0) {
    double zz[6];
    double yl = yf[2041];
    #pragma unroll
    for (int s = 0; s < 3; s++) { zz[2 * s] = c.zi0[s] * yl; zz[2 * s + 1] = c.zi1[s] * yl; }
    for (int kk = 0; kk < 64; kk++) {
      #pragma unroll
      for (int i = 0; i < 6; i++) Zs[kk][i] = zz[i];
      double nz[6];
      #pragma unroll
      for (int i = 0; i < 6; i++) {
        double s = Fs[kk][i];
        #pragma unroll
        for (int j = 0; j < 6; j++) s += c.A32[i * 6 + j] * zz[j];
        nz[i] = s;
      }
      #pragma unroll
      for (int i = 0; i < 6; i++) zz[i] = nz[i];
    }
  }
  __syncthreads();
  #pragma unroll
  for (int i = 0; i < 6; i++) z[i] = Zs[k][i];
  for (int i = 0; i < 32; i++) {
    double y = step(z, rin(t0 + i));
    int j = t0 + i;
    if (j >= 21 && j <= 2020) x[2020 - j] = (float)y;
  }
}

// ---------------- kernel 3: polyphase resample + tanh + per-row normalize ----
__global__ __launch_bounds__(256) void k_resample_norm(const float* __restrict__ xf,
                                                       float* __restrict__ xn,
                                                       FirArg fa) {
  int r = blockIdx.x;                         // 640 rows
  const float* x = xf + (size_t)r * 2000;
  float vals[5];
  #pragma unroll
  for (int kk = 0; kk < 5; kk++) {
    int o = threadIdx.x + kk * 256;           // 1280 outputs per row
    int P = 25 * (o + 11);
    int phase = P & 15;
    float acc = 0.f;
    for (int m = phase; m <= 525; m += 16) {
      int idx = (P - m) >> 4;
      if (idx >= 0 && idx < 2000) acc += fa.h[m] * x[idx];
    }
    vals[kk] = tanhf(acc);
  }
  double s = 0.0, ss = 0.0;
  #pragma unroll
  for (int kk = 0; kk < 5; kk++) {
    s += (double)vals[kk]; ss += (double)vals[kk] * (double)vals[kk];
  }
  s = waveReduceSum(s); ss = waveReduceSum(ss);
  __shared__ double red[8];
  int wid = threadIdx.x >> 6, lane = threadIdx.x & 63;
  if (lane == 0) { red[wid] = s; red[4 + wid] = ss; }
  __syncthreads();
  double S = red[0] + red[1] + red[2] + red[3];
  double SS = red[4] + red[5] + red[6] + red[7];
  double mean = S / 1280.0;
  double var = (SS - 1280.0 * mean * mean) / 1279.0;
  double sd = fmax(sqrt(fmax(var, 0.0)), 1e-6);
  float fmean = (float)mean, finv = (float)(1.0 / sd);
  #pragma unroll
  for (int kk = 0; kk < 5; kk++)
    xn[(size_t)r * 1280 + threadIdx.x + kk * 256] = (vals[kk] - fmean) * finv;
}

// ---------------- kernel 4: conv1d + relu + LN + PE(inline) + QKV (fused) -----
__global__ __launch_bounds__(256) void k_conv_ln_pe_qkv(const float* __restrict__ xn,
    const float* __restrict__ cw, const float* __restrict__ cb,
    const float* __restrict__ g0, const float* __restrict__ bt0,
    const float* __restrict__ wqkv, const float* __restrict__ bqkv,
    float* __restrict__ x0,
    float* __restrict__ Q, float* __restrict__ K, float* __restrict__ V) {
  __shared__ float w[480], bias[16], gg[16], gb[16];
  __shared__ float wq[768], bq[48];
  for (int i = threadIdx.x; i < 480; i += 256) w[i] = cw[i];
  for (int i = threadIdx.x; i < 768; i += 256) wq[i] = wqkv[i];
  if (threadIdx.x < 16) {
    bias[threadIdx.x] = cb[threadIdx.x];
    gg[threadIdx.x] = g0[threadIdx.x];
    gb[threadIdx.x] = bt0[threadIdx.x];
  }
  if (threadIdx.x < 48) bq[threadIdx.x] = bqkv[threadIdx.x];
  __syncthreads();
  int idx = blockIdx.x * 256 + threadIdx.x;
  int b = idx / 1280, t = idx % 1280;
  const float* xb = xn + (size_t)b * 10 * 1280;
  float in[10][3];
  #pragma unroll
  for (int i = 0; i < 10; i++)
    #pragma unroll
    for (int k = 0; k < 3; k++) {
      int tt = t - 1 + k;
      in[i][k] = (tt >= 0 && tt < 1280) ? xb[i * 1280 + tt] : 0.f;
    }
  float o[16];
  #pragma unroll
  for (int oc = 0; oc < 16; oc++) {
    float a = bias[oc];
    #pragma unroll
    for (int i = 0; i < 10; i++)
      #pragma unroll
      for (int k = 0; k < 3; k++) a += in[i][k] * w[oc * 30 + i * 3 + k];
    o[oc] = fmaxf(a, 0.f);
  }
  float mu = 0.f;
  #pragma unroll
  for (int d = 0; d < 16; d++) mu += o[d];
  mu *= (1.f / 16.f);
  float var = 0.f;
  #pragma unroll
  for (int d = 0; d < 16; d++) { float dd = o[d] - mu; var += dd * dd; }
  var *= (1.f / 16.f);
  float inv = 1.f / sqrtf(var + 1e-5f);
  float xv[16];
  float* outp = x0 + (size_t)idx * 16;
  #pragma unroll
  for (int d = 0; d < 16; d++) {
    // PE inline (f64 trig, matches reference f64 table build to f32 rounding)
    int j = d >> 1;
    double dv = exp(-((double)(2 * j)) * 0.5756462732485114); // ln(10000)/16
    double ang = (double)t * dv;
    float pe = (float)((d & 1) ? cos(ang) : sin(ang));
    xv[d] = (o[d] - mu) * inv * gg[d] + gb[d] + pe;
    outp[d] = xv[d];
  }
  float* qp = Q + (size_t)idx * 16;
  float* kp = K + (size_t)idx * 16;
  float* vp = V + (size_t)idx * 16;
  #pragma unroll
  for (int j = 0; j < 16; j++) {
    float a = bq[j];
    #pragma unroll
    for (int d = 0; d < 16; d++) a += xv[d] * wq[j * 16 + d];
    qp[j] = a;
  }
  #pragma unroll
  for (int j = 0; j < 16; j++) {
    float a = bq[16 + j];
    #pragma unroll
    for (int d = 0; d < 16; d++) a += xv[d] * wq[(16 + j) * 16 + d];
    kp[j] = a;
  }
  #pragma unroll
  for (int j = 0; j < 16; j++) {
    float a = bq[32 + j];
    #pragma unroll
    for (int d = 0; d < 16; d++) a += xv[d] * wq[(32 + j) * 16 + d];
    vp[j] = a;
  }
}

// ---------------- kernel 5: MFMA attention ------------------------------------
// Per wave = one 16-row Q-tile; block = 4 waves = 64 rows; grid = 64*20.
// S^T-tile = mfma_16x16x32_f16(A=K-tile [key][d pad32], B=Q^T) -> C:
//   S^T[key=quad*4+reg][qrow=lane&15]  (verified C/D layout)
// p = exp(0.25*s - 12) (0.25 folded into Q); P^T -> per-wave LDS (b64 write),
// read back in A-layout A[m=lane&15][k=quad*8+j] (b128, m120-verified pattern);
// PV = mfma(A=P, B=V^T from LDS) contracting 32 keys -> out[qrow][d] C-frag.
// LDS strides padded (40/72/40 halves) for <=2-way banking.
#define ATT_SHIFT 12.0f
__global__ __launch_bounds__(256) void k_attn_mfma(const float* __restrict__ Q,
    const float* __restrict__ K, const float* __restrict__ V,
    float* __restrict__ A) {
  __shared__ __align__(16) _Float16 Ks[64 * 40];   // [key][d], d 16..31 zero
  __shared__ __align__(16) _Float16 Vt[16 * 72];   // [d][key]
  __shared__ __align__(16) _Float16 Pld[4][16 * 40]; // per-wave [qrow][key32]
  int tid = threadIdx.x;
  int b  = blockIdx.x / 20;
  int rg = blockIdx.x % 20;
  int wv = tid >> 6;
  int lane = tid & 63;
  int col = lane & 15;
  int quad = lane >> 4;
  size_t base = (size_t)b * 1280;
  int row0 = rg * 64 + wv * 16;

  // Q B-frag: B[k=quad*8+j][n=col] = 0.25*Q[row0+col][quad*8+j]; quads 2,3 = 0
  f16x8 qf;
  #pragma unroll
  for (int j = 0; j < 8; j++) qf[j] = (_Float16)0.f;
  if (quad < 2) {
    const float* qp = Q + (base + row0 + col) * 16 + quad * 8;
    #pragma unroll
    for (int j = 0; j < 8; j++) qf[j] = (_Float16)(0.25f * qp[j]);
  }
  f32x4 oacc = {0.f, 0.f, 0.f, 0.f};
  float lacc = 0.f;

  for (int s = 0; s < 20; s++) {
    __syncthreads();
    {
      int key = tid >> 2, part = tid & 3;
      const float* kp = K + (base + s * 64 + key) * 16 + part * 4;
      f16x4 hk, hz;
      #pragma unroll
      for (int j = 0; j < 4; j++) { hk[j] = (_Float16)kp[j]; hz[j] = (_Float16)0.f; }
      *(f16x4*)&Ks[key * 40 + part * 4] = hk;
      *(f16x4*)&Ks[key * 40 + 16 + part * 4] = hz;
      const float* vp = V + (base + s * 64 + key) * 16 + part * 4;
      #pragma unroll
      for (int j = 0; j < 4; j++) Vt[(part * 4 + j) * 72 + key] = (_Float16)vp[j];
    }
    __syncthreads();
    #pragma unroll
    for (int c = 0; c < 2; c++) {
      #pragma unroll
      for (int t = 0; t < 2; t++) {
        int keyoff = c * 32 + t * 16;
        f16x8 af = *(f16x8*)&Ks[(keyoff + col) * 40 + quad * 8];
        f32x4 sf = {0.f, 0.f, 0.f, 0.f};
        sf = __builtin_amdgcn_mfma_f32_16x16x32_f16(af, qf, sf, 0, 0, 0);
        f16x4 ph;
        float psum = 0.f;
        #pragma unroll
        for (int r = 0; r < 4; r++) {
          float p = __expf(sf[r] - ATT_SHIFT);
          psum += p;
          ph[r] = (_Float16)p;
        }
        lacc += psum;
        *(f16x4*)&Pld[wv][col * 40 + t * 16 + quad * 4] = ph;
      }
      __syncthreads();
      f16x8 pf = *(f16x8*)&Pld[wv][col * 40 + quad * 8];
      f16x8 vf = *(f16x8*)&Vt[col * 72 + c * 32 + quad * 8];
      oacc = __builtin_amdgcn_mfma_f32_16x16x32_f16(pf, vf, oacc, 0, 0, 0);
      __syncthreads();
    }
  }
  // l[qrow=col]: merge quads
  lacc += __shfl_xor(lacc, 16, 64);
  lacc += __shfl_xor(lacc, 32, 64);
  // out frag: out[qrow=quad*4+r][d=col]
  #pragma unroll
  for (int r = 0; r < 4; r++) {
    float lr = __shfl(lacc, quad * 4 + r, 64);
    A[(base + row0 + quad * 4 + r) * 16 + col] = oacc[r] / lr;
  }
}

// ---------------- kernel 6: combine + wo + LN1 + FFN + LN2 + pool (fused) -----
__global__ __launch_bounds__(256) void k_combine_pool(
    const float* __restrict__ A, const float* __restrict__ x0,
    const float* __restrict__ wo, const float* __restrict__ bo,
    const float* __restrict__ w1, const float* __restrict__ b1,
    const float* __restrict__ w2, const float* __restrict__ b2,
    const float* __restrict__ g1, const float* __restrict__ bb1,
    const float* __restrict__ g2, const float* __restrict__ bb2,
    const float* __restrict__ wfc, const float* __restrict__ bfc,
    float* __restrict__ out) {
  __shared__ float swo[256], sw1[512], sw2[512];
  __shared__ float sbo[16], sb1[32], sb2[16], sg1[16], sbb1[16], sg2[16], sbb2[16];
  __shared__ float swf[16];
  int tid = threadIdx.x;
  swo[tid] = wo[tid];
  for (int i = tid; i < 512; i += 256) { sw1[i] = w1[i]; sw2[i] = w2[i]; }
  if (tid < 16) {
    sbo[tid] = bo[tid]; sb2[tid] = b2[tid];
    sg1[tid] = g1[tid]; sbb1[tid] = bb1[tid];
    sg2[tid] = g2[tid]; sbb2[tid] = bb2[tid];
    swf[tid] = wfc[tid];
  }
  if (tid < 32) sb1[tid] = b1[tid];
  __syncthreads();

  int idx = blockIdx.x * 256 + tid;          // [0, 81920)
  int bb = blockIdx.x / 5;
  const float* pa = A + (size_t)idx * 16;
  float a[16];
  #pragma unroll
  for (int d = 0; d < 16; d++) a[d] = pa[d];
  float h[16];
  const float* xr = x0 + (size_t)idx * 16;
  #pragma unroll
  for (int d = 0; d < 16; d++) {
    float o = sbo[d];
    #pragma unroll
    for (int e = 0; e < 16; e++) o += a[e] * swo[d * 16 + e];
    h[d] = xr[d] + o;
  }
  float mu = 0.f;
  #pragma unroll
  for (int d = 0; d < 16; d++) mu += h[d];
  mu *= (1.f / 16.f);
  float var = 0.f;
  #pragma unroll
  for (int d = 0; d < 16; d++) { float dd = h[d] - mu; var += dd * dd; }
  var *= (1.f / 16.f);
  float inv = 1.f / sqrtf(var + 1e-5f);
  float x1[16];
  #pragma unroll
  for (int d = 0; d < 16; d++) x1[d] = (h[d] - mu) * inv * sg1[d] + sbb1[d];
  float t1[32];
  #pragma unroll
  for (int j = 0; j < 32; j++) {
    float u = sb1[j];
    #pragma unroll
    for (int d = 0; d < 16; d++) u += x1[d] * sw1[j * 16 + d];
    t1[j] = fmaxf(u, 0.f);
  }
  float h2[16];
  #pragma unroll
  for (int d = 0; d < 16; d++) {
    float u = sb2[d];
    #pragma unroll
    for (int j = 0; j < 32; j++) u += t1[j] * sw2[d * 32 + j];
    h2[d] = x1[d] + u;
  }
  mu = 0.f;
  #pragma unroll
  for (int d = 0; d < 16; d++) mu += h2[d];
  mu *= (1.f / 16.f);
  var = 0.f;
  #pragma unroll
  for (int d = 0; d < 16; d++) { float dd = h2[d] - mu; var += dd * dd; }
  var *= (1.f / 16.f);
  inv = 1.f / sqrtf(var + 1e-5f);
  // x2 row dot wfc (x2 never materialized)
  float pv = 0.f;
  #pragma unroll
  for (int d = 0; d < 16; d++)
    pv += ((h2[d] - mu) * inv * sg2[d] + sbb2[d]) * swf[d];
  // block-reduce pv -> one atomicAdd per block
  double part = waveReduceSum((double)pv);
  __shared__ double red[4];
  int wid = tid >> 6, lane = tid & 63;
  if (lane == 0) red[wid] = part;
  __syncthreads();
  if (tid == 0) {
    double S = red[0] + red[1] + red[2] + red[3];
    float add = (float)(S / 1280.0);
    if (blockIdx.x % 5 == 0) add += bfc[0];
    atomicAdd(&out[bb], add);
  }
}

// ---------------- launch ------------------------------------------------------
extern "C" void kernel_launch(void* const* d_in, const int* in_sizes, int n_in,
                              void* d_out, int out_size, void* d_ws, size_t ws_size,
                              hipStream_t stream) {
  const float* x    = (const float*)d_in[0];
  const float* cw   = (const float*)d_in[1];
  const float* cb   = (const float*)d_in[2];
  const float* g0   = (const float*)d_in[3];
  const float* bt0  = (const float*)d_in[4];
  const float* wqkv = (const float*)d_in[5];
  const float* bqkv = (const float*)d_in[6];
  const float* wo   = (const float*)d_in[7];
  const float* bo   = (const float*)d_in[8];
  const float* w1   = (const float*)d_in[9];
  const float* b1   = (const float*)d_in[10];
  const float* w2   = (const float*)d_in[11];
  const float* b2   = (const float*)d_in[12];
  const float* g1   = (const float*)d_in[13];
  const float* bb1  = (const float*)d_in[14];
  const float* g2   = (const float*)d_in[15];
  const float* bb2  = (const float*)d_in[16];
  const float* wfc  = (const float*)d_in[17];
  const float* bfc  = (const float*)d_in[18];
  float* out = (float*)d_out;

  float* ws = (float*)d_ws;
  float* xs = ws;                       // 640*2000 = 1,280,000 (filtered in-place;
                                        // dead after k_resample_norm -> reused as A)
  float* y1 = xs + 1280000;             // spacer (dead)
  float* xn = y1 + 1306880;             // 640*1280   =   819,200
  float* x0 = xn + 819200;              // 64*1280*16 = 1,310,720
  float* Q  = x0 + 1310720;
  float* Kb = Q  + 1310720;
  float* Vb = Kb + 1310720;             // total ~36 MB
  float* Abuf = ws;                     // attention output (reuses dead xs)

  FiltArg fc; FirArg fa;
  build_filt(fc);
  design_fir(fa);

  k_chansel<<<(64 * 2000 + 255) / 256, 256, 0, stream>>>(x, xs);
  k_filtfilt<<<640, 64, 0, stream>>>(xs, fc);
  k_resample_norm<<<640, 256, 0, stream>>>(xs, xn, fa);
  k_conv_ln_pe_qkv<<<320, 256, 0, stream>>>(xn, cw, cb, g0, bt0, wqkv, bqkv,
                                            x0, Q, Kb, Vb);
  k_attn_mfma<<<1280, 256, 0, stream>>>(Q, Kb, Vb, Abuf);
  hipMemsetAsync(out, 0, 64 * sizeof(float), stream);
  k_combine_pool<<<320, 256, 0, stream>>>(Abuf, x0, wo, bo, w1, b1, w2, b2,
                                          g1, bb1, g2, bb2, wfc, bfc, out);
}

// Round 7
// 300.861 us; speedup vs baseline: 1.6268x; 1.0395x over previous
//
#include <hip/hip_runtime.h>
#include <cmath>
#include <complex>
#include <algorithm>

#ifndef M_PI
#define M_PI 3.14159265358979323846
#endif

typedef _Float16 f16x8 __attribute__((ext_vector_type(8)));
typedef _Float16 f16x4 __attribute__((ext_vector_type(4)));
typedef float f32x4 __attribute__((ext_vector_type(4)));

// ---------------- coefficient structs (passed by value as kernel args) ---------
struct FiltArg {
  double b0[3], b1[3], b2[3], a1[3], a2[3];
  double zi0[3], zi1[3];
  double A32[36];              // (state-transition matrix)^32, 6x6 row-major
};
struct FirArg { float h[526]; };  // 25 leading zeros + 501-tap kaiser-sinc, *UP

// ---------------- host-side filter design (exact replica of reference) --------
static void design_sos(FiltArg& sa) {
  const int order = 6;
  const double wn = 0.5 / 50.0;
  const double fs = 2.0;
  double warped = 2.0 * fs * std::tan(M_PI * wn / fs);
  std::complex<double> p[6];
  for (int i = 0; i < order; i++) {
    int m = -order + 1 + 2 * i;                      // -5,-3,-1,1,3,5
    p[i] = -std::exp(std::complex<double>(0.0, M_PI * m / (2.0 * order)));
  }
  std::complex<double> prod1(1, 0);
  for (int i = 0; i < 6; i++) prod1 *= -p[i];
  double k = (1.0 / prod1).real();
  for (int i = 0; i < 6; i++) p[i] = warped / p[i];
  const double fs2 = 2.0 * fs;
  std::complex<double> num(1, 0), den(1, 0);
  for (int i = 0; i < 6; i++) { num *= fs2; den *= (fs2 - p[i]); }
  k *= (num / den).real();
  for (int i = 0; i < 6; i++) p[i] = (fs2 + p[i]) / (fs2 - p[i]);
  std::complex<double> pp[3]; int n = 0;
  for (int i = 0; i < 6; i++) if (p[i].imag() > 0) pp[n++] = p[i];
  std::stable_sort(pp, pp + 3,
    [](const std::complex<double>& A, const std::complex<double>& B) {
      return std::fabs(std::abs(A) - 1.0) > std::fabs(std::abs(B) - 1.0);
    });
  double sos[3][6];
  for (int s = 0; s < 3; s++) {
    double g = (s == 0) ? k : 1.0;
    sos[s][0] = g; sos[s][1] = -2.0 * g; sos[s][2] = g;
    sos[s][3] = 1.0; sos[s][4] = -2.0 * pp[s].real(); sos[s][5] = std::norm(pp[s]);
  }
  double scale = 1.0;
  for (int s = 0; s < 3; s++) {
    double b0 = sos[s][0], b1 = sos[s][1], b2 = sos[s][2];
    double a1 = sos[s][4], a2 = sos[s][5];
    double det = 1.0 + a1 + a2;                      // det of [[1+a1,-1],[a2,1]]
    double r0 = b1 - a1 * b0, r1 = b2 - a2 * b0;
    double z0 = (r0 + r1) / det;
    double z1 = ((1.0 + a1) * r1 - a2 * r0) / det;
    sa.b0[s] = b0; sa.b1[s] = b1; sa.b2[s] = b2; sa.a1[s] = a1; sa.a2[s] = a2;
    sa.zi0[s] = scale * z0; sa.zi1[s] = scale * z1;
    scale *= (b0 + b1 + b2) / (1.0 + a1 + a2);
  }
}

static double host_step(const FiltArg& c, double z[6], double v) {
  for (int s = 0; s < 3; s++) {
    double y = c.b0[s] * v + z[2 * s];
    z[2 * s]     = c.b1[s] * v - c.a1[s] * y + z[2 * s + 1];
    z[2 * s + 1] = c.b2[s] * v - c.a2[s] * y;
    v = y;
  }
  return v;
}

static void build_filt(FiltArg& c) {
  design_sos(c);
  double A[36];
  for (int j = 0; j < 6; j++) {
    double z[6] = {0, 0, 0, 0, 0, 0};
    z[j] = 1.0;
    host_step(c, z, 0.0);
    for (int i = 0; i < 6; i++) A[i * 6 + j] = z[i];
  }
  double M[36], T[36];
  for (int i = 0; i < 36; i++) M[i] = A[i];
  for (int sq = 0; sq < 5; sq++) {
    for (int i = 0; i < 6; i++)
      for (int j = 0; j < 6; j++) {
        double s = 0.0;
        for (int kk = 0; kk < 6; kk++) s += M[i * 6 + kk] * M[kk * 6 + j];
        T[i * 6 + j] = s;
      }
    for (int i = 0; i < 36; i++) M[i] = T[i];
  }
  for (int i = 0; i < 36; i++) c.A32[i] = M[i];
}

static double bessel_i0(double x) {
  double s = 1.0, t = 1.0;
  for (int k = 1; k < 64; k++) {
    double u = x / (2.0 * k);
    t *= u * u; s += t;
    if (t < 1e-18 * s) break;
  }
  return s;
}

static void design_fir(FirArg& fa) {
  double h[501];
  const double fc = 1.0 / 25.0;
  double denom = bessel_i0(5.0);
  double sum = 0.0;
  for (int nn = 0; nn < 501; nn++) {
    double m = nn - 250.0;
    double xx = fc * m;
    double snc = (nn == 250) ? 1.0 : std::sin(M_PI * xx) / (M_PI * xx);
    double r = (2.0 * nn) / 500.0 - 1.0;
    double w = bessel_i0(5.0 * std::sqrt(std::max(0.0, 1.0 - r * r))) / denom;
    h[nn] = fc * snc * w; sum += h[nn];
  }
  for (int nn = 0; nn < 25; nn++) fa.h[nn] = 0.0f;          // n_pre_pad = 25
  for (int nn = 0; nn < 501; nn++) fa.h[25 + nn] = (float)(h[nn] / sum * 16.0);
}

// ---------------- device helpers ----------------
__device__ inline double waveReduceSum(double v) {
  #pragma unroll
  for (int off = 32; off > 0; off >>= 1) v += __shfl_down(v, off, 64);
  return v;
}

// ---------------- kernel 1: chansel + demean + filtfilt (fused) ---------------
// One block (64 threads) per row. LDS strides padded so that thread k's chunk
// accesses spread across all banks:
//   XR (f32, chunk stride 33): bank = (k+i) mod 32  -> conflict-free
//   YF (f64, chunk stride 33): 8B-pair = (k+i) mod 16 -> 4-way = b64 HW floor
//   Fs/Zs [64][7] (f64): pair = (7k+i) mod 16, gcd(7,16)=1 -> uniform
#define XR(t) xr[(t) + ((t) >> 5)]
#define YF(t) yf[(t) + ((t) >> 5)]
__global__ __launch_bounds__(64) void k_filtfilt(const float* __restrict__ xin,
                                                 float* __restrict__ xs, FiltArg c) {
  __shared__ float xr[2064];      // demeaned input row (padded)
  __shared__ double yf[2112];     // forward filter output (padded)
  __shared__ double Fs[64][7];
  __shared__ double Zs[64][7];
  int r = blockIdx.x;             // 640 rows = (b, c)
  int b = r / 10, csel = r % 10;
  int k = threadIdx.x;
  const int ch[10] = {126, 125, 48, 112, 67, 93, 10, 61, 39, 108};
  const float* xb = xin + (size_t)b * 128 * 2000;
  const float* xc = xb + (size_t)ch[csel] * 2000;
  float* xo = xs + (size_t)r * 2000;

  // stage demeaned row (coalesced global reads; L2-hot across the 10 blocks/batch)
  for (int t = k; t < 2000; t += 64) {
    float s = 0.f;
    #pragma unroll
    for (int cc = 0; cc < 10; cc++) s += xb[ch[cc] * 2000 + t];
    XR(t) = xc[t] - 0.1f * s;
  }
  __syncthreads();

  double b0[3], b1[3], b2[3], a1[3], a2[3];
  #pragma unroll
  for (int s = 0; s < 3; s++) {
    b0[s] = c.b0[s]; b1[s] = c.b1[s]; b2[s] = c.b2[s];
    a1[s] = c.a1[s]; a2[s] = c.a2[s];
  }
  auto step = [&](double* z, double v) -> double {
    #pragma unroll
    for (int s = 0; s < 3; s++) {
      double y = b0[s] * v + z[2 * s];
      z[2 * s]     = b1[s] * v - a1[s] * y + z[2 * s + 1];
      z[2 * s + 1] = b2[s] * v - a2[s] * y;
      v = y;
    }
    return v;
  };

  double xf0 = (double)XR(0), xlast = (double)XR(1999);
  auto ein = [&](int t) -> double {
    if (t < 21)   return 2.0 * xf0 - (double)XR(21 - t);
    if (t < 2021) return (double)XR(t - 21);
    if (t < 2042) return 2.0 * xlast - (double)XR(4019 - t);
    return 0.0;
  };

  int t0 = k * 32;
  double z[6];

  // ---- forward: pass 1 (zero state) ----
  #pragma unroll
  for (int i = 0; i < 6; i++) z[i] = 0.0;
  for (int i = 0; i < 32; i++) step(z, ein(t0 + i));
  #pragma unroll
  for (int i = 0; i < 6; i++) Fs[k][i] = z[i];
  __syncthreads();
  if (k == 0) {
    double zz[6];
    double e0 = 2.0 * xf0 - (double)XR(21);
    #pragma unroll
    for (int s = 0; s < 3; s++) { zz[2 * s] = c.zi0[s] * e0; zz[2 * s + 1] = c.zi1[s] * e0; }
    for (int kk = 0; kk < 64; kk++) {
      #pragma unroll
      for (int i = 0; i < 6; i++) Zs[kk][i] = zz[i];
      double nz[6];
      #pragma unroll
      for (int i = 0; i < 6; i++) {
        double s = Fs[kk][i];
        #pragma unroll
        for (int j = 0; j < 6; j++) s += c.A32[i * 6 + j] * zz[j];
        nz[i] = s;
      }
      #pragma unroll
      for (int i = 0; i < 6; i++) zz[i] = nz[i];
    }
  }
  __syncthreads();
  // ---- forward: pass 2 (true state), emit yf ----
  #pragma unroll
  for (int i = 0; i < 6; i++) z[i] = Zs[k][i];
  for (int i = 0; i < 32; i++) YF(t0 + i) = step(z, ein(t0 + i));
  __syncthreads();

  // ---- backward over reversed yf ----
  auto rin = [&](int j) -> double { return (j <= 2041) ? YF(2041 - j) : 0.0; };
  #pragma unroll
  for (int i = 0; i < 6; i++) z[i] = 0.0;
  for (int i = 0; i < 32; i++) step(z, rin(t0 + i));
  #pragma unroll
  for (int i = 0; i < 6; i++) Fs[k][i] = z[i];
  __syncthreads();
  if (k == 0) {
    double zz[6];
    double yl = YF(2041);
    #pragma unroll
    for (int s = 0; s < 3; s++) { zz[2 * s] = c.zi0[s] * yl; zz[2 * s + 1] = c.zi1[s] * yl; }
    for (int kk = 0; kk < 64; kk++) {
      #pragma unroll
      for (int i = 0; i < 6; i++) Zs[kk][i] = zz[i];
      double nz[6];
      #pragma unroll
      for (int i = 0; i < 6; i++) {
        double s = Fs[kk][i];
        #pragma unroll
        for (int j = 0; j < 6; j++) s += c.A32[i * 6 + j] * zz[j];
        nz[i] = s;
      }
      #pragma unroll
      for (int i = 0; i < 6; i++) zz[i] = nz[i];
    }
  }
  __syncthreads();
  #pragma unroll
  for (int i = 0; i < 6; i++) z[i] = Zs[k][i];
  for (int i = 0; i < 32; i++) {
    double y = step(z, rin(t0 + i));
    int j = t0 + i;
    if (j >= 21 && j <= 2020) xo[2020 - j] = (float)y;   // reversed + trimmed
  }
}

// ---------------- kernel 2: polyphase resample + tanh + per-row normalize ----
// Row + FIR taps staged in LDS (tap loop was 2 scattered global loads/tap).
__global__ __launch_bounds__(256) void k_resample_norm(const float* __restrict__ xf,
                                                       float* __restrict__ xn,
                                                       FirArg fa) {
  __shared__ float xl[2000];
  __shared__ float hl[526];
  int r = blockIdx.x;                         // 640 rows
  const float* x = xf + (size_t)r * 2000;
  for (int i = threadIdx.x; i < 2000; i += 256) xl[i] = x[i];
  for (int i = threadIdx.x; i < 526; i += 256) hl[i] = fa.h[i];
  __syncthreads();
  float vals[5];
  #pragma unroll
  for (int kk = 0; kk < 5; kk++) {
    int o = threadIdx.x + kk * 256;           // 1280 outputs per row
    int P = 25 * (o + 11);
    int phase = P & 15;
    float acc = 0.f;
    for (int m = phase; m <= 525; m += 16) {
      int idx = (P - m) >> 4;
      if (idx >= 0 && idx < 2000) acc += hl[m] * xl[idx];
    }
    vals[kk] = tanhf(acc);
  }
  double s = 0.0, ss = 0.0;
  #pragma unroll
  for (int kk = 0; kk < 5; kk++) {
    s += (double)vals[kk]; ss += (double)vals[kk] * (double)vals[kk];
  }
  s = waveReduceSum(s); ss = waveReduceSum(ss);
  __shared__ double red[8];
  int wid = threadIdx.x >> 6, lane = threadIdx.x & 63;
  if (lane == 0) { red[wid] = s; red[4 + wid] = ss; }
  __syncthreads();
  double S = red[0] + red[1] + red[2] + red[3];
  double SS = red[4] + red[5] + red[6] + red[7];
  double mean = S / 1280.0;
  double var = (SS - 1280.0 * mean * mean) / 1279.0;
  double sd = fmax(sqrt(fmax(var, 0.0)), 1e-6);
  float fmean = (float)mean, finv = (float)(1.0 / sd);
  #pragma unroll
  for (int kk = 0; kk < 5; kk++)
    xn[(size_t)r * 1280 + threadIdx.x + kk * 256] = (vals[kk] - fmean) * finv;
}

// ---------------- kernel 3: conv1d + relu + LN + PE(inline) + QKV (fused) -----
__global__ __launch_bounds__(256) void k_conv_ln_pe_qkv(const float* __restrict__ xn,
    const float* __restrict__ cw, const float* __restrict__ cb,
    const float* __restrict__ g0, const float* __restrict__ bt0,
    const float* __restrict__ wqkv, const float* __restrict__ bqkv,
    float* __restrict__ x0,
    float* __restrict__ Q, float* __restrict__ K, float* __restrict__ V) {
  __shared__ float w[480], bias[16], gg[16], gb[16];
  __shared__ float wq[768], bq[48];
  for (int i = threadIdx.x; i < 480; i += 256) w[i] = cw[i];
  for (int i = threadIdx.x; i < 768; i += 256) wq[i] = wqkv[i];
  if (threadIdx.x < 16) {
    bias[threadIdx.x] = cb[threadIdx.x];
    gg[threadIdx.x] = g0[threadIdx.x];
    gb[threadIdx.x] = bt0[threadIdx.x];
  }
  if (threadIdx.x < 48) bq[threadIdx.x] = bqkv[threadIdx.x];
  __syncthreads();
  int idx = blockIdx.x * 256 + threadIdx.x;
  int b = idx / 1280, t = idx % 1280;
  const float* xb = xn + (size_t)b * 10 * 1280;
  float in[10][3];
  #pragma unroll
  for (int i = 0; i < 10; i++)
    #pragma unroll
    for (int k = 0; k < 3; k++) {
      int tt = t - 1 + k;
      in[i][k] = (tt >= 0 && tt < 1280) ? xb[i * 1280 + tt] : 0.f;
    }
  float o[16];
  #pragma unroll
  for (int oc = 0; oc < 16; oc++) {
    float a = bias[oc];
    #pragma unroll
    for (int i = 0; i < 10; i++)
      #pragma unroll
      for (int k = 0; k < 3; k++) a += in[i][k] * w[oc * 30 + i * 3 + k];
    o[oc] = fmaxf(a, 0.f);
  }
  float mu = 0.f;
  #pragma unroll
  for (int d = 0; d < 16; d++) mu += o[d];
  mu *= (1.f / 16.f);
  float var = 0.f;
  #pragma unroll
  for (int d = 0; d < 16; d++) { float dd = o[d] - mu; var += dd * dd; }
  var *= (1.f / 16.f);
  float inv = 1.f / sqrtf(var + 1e-5f);
  float xv[16];
  float* outp = x0 + (size_t)idx * 16;
  #pragma unroll
  for (int d = 0; d < 16; d++) {
    int j = d >> 1;
    double dv = exp(-((double)(2 * j)) * 0.5756462732485114); // ln(10000)/16
    double ang = (double)t * dv;
    float pe = (float)((d & 1) ? cos(ang) : sin(ang));
    xv[d] = (o[d] - mu) * inv * gg[d] + gb[d] + pe;
    outp[d] = xv[d];
  }
  float* qp = Q + (size_t)idx * 16;
  float* kp = K + (size_t)idx * 16;
  float* vp = V + (size_t)idx * 16;
  #pragma unroll
  for (int j = 0; j < 16; j++) {
    float a = bq[j];
    #pragma unroll
    for (int d = 0; d < 16; d++) a += xv[d] * wq[j * 16 + d];
    qp[j] = a;
  }
  #pragma unroll
  for (int j = 0; j < 16; j++) {
    float a = bq[16 + j];
    #pragma unroll
    for (int d = 0; d < 16; d++) a += xv[d] * wq[(16 + j) * 16 + d];
    kp[j] = a;
  }
  #pragma unroll
  for (int j = 0; j < 16; j++) {
    float a = bq[32 + j];
    #pragma unroll
    for (int d = 0; d < 16; d++) a += xv[d] * wq[(32 + j) * 16 + d];
    vp[j] = a;
  }
}

// ---------------- kernel 4: MFMA attention ------------------------------------
#define ATT_SHIFT 12.0f
__global__ __launch_bounds__(256) void k_attn_mfma(const float* __restrict__ Q,
    const float* __restrict__ K, const float* __restrict__ V,
    float* __restrict__ A) {
  __shared__ __align__(16) _Float16 Ks[64 * 40];   // [key][d], d 16..31 zero
  __shared__ __align__(16) _Float16 Vt[16 * 72];   // [d][key]
  __shared__ __align__(16) _Float16 Pld[4][16 * 40]; // per-wave [qrow][key32]
  int tid = threadIdx.x;
  int b  = blockIdx.x / 20;
  int rg = blockIdx.x % 20;
  int wv = tid >> 6;
  int lane = tid & 63;
  int col = lane & 15;
  int quad = lane >> 4;
  size_t base = (size_t)b * 1280;
  int row0 = rg * 64 + wv * 16;

  f16x8 qf;
  #pragma unroll
  for (int j = 0; j < 8; j++) qf[j] = (_Float16)0.f;
  if (quad < 2) {
    const float* qp = Q + (base + row0 + col) * 16 + quad * 8;
    #pragma unroll
    for (int j = 0; j < 8; j++) qf[j] = (_Float16)(0.25f * qp[j]);
  }
  f32x4 oacc = {0.f, 0.f, 0.f, 0.f};
  float lacc = 0.f;

  for (int s = 0; s < 20; s++) {
    __syncthreads();
    {
      int key = tid >> 2, part = tid & 3;
      const float* kp = K + (base + s * 64 + key) * 16 + part * 4;
      f16x4 hk, hz;
      #pragma unroll
      for (int j = 0; j < 4; j++) { hk[j] = (_Float16)kp[j]; hz[j] = (_Float16)0.f; }
      *(f16x4*)&Ks[key * 40 + part * 4] = hk;
      *(f16x4*)&Ks[key * 40 + 16 + part * 4] = hz;
      const float* vp = V + (base + s * 64 + key) * 16 + part * 4;
      #pragma unroll
      for (int j = 0; j < 4; j++) Vt[(part * 4 + j) * 72 + key] = (_Float16)vp[j];
    }
    __syncthreads();
    #pragma unroll
    for (int c = 0; c < 2; c++) {
      #pragma unroll
      for (int t = 0; t < 2; t++) {
        int keyoff = c * 32 + t * 16;
        f16x8 af = *(f16x8*)&Ks[(keyoff + col) * 40 + quad * 8];
        f32x4 sf = {0.f, 0.f, 0.f, 0.f};
        sf = __builtin_amdgcn_mfma_f32_16x16x32_f16(af, qf, sf, 0, 0, 0);
        f16x4 ph;
        float psum = 0.f;
        #pragma unroll
        for (int r = 0; r < 4; r++) {
          float p = __expf(sf[r] - ATT_SHIFT);
          psum += p;
          ph[r] = (_Float16)p;
        }
        lacc += psum;
        *(f16x4*)&Pld[wv][col * 40 + t * 16 + quad * 4] = ph;
      }
      __syncthreads();
      f16x8 pf = *(f16x8*)&Pld[wv][col * 40 + quad * 8];
      f16x8 vf = *(f16x8*)&Vt[col * 72 + c * 32 + quad * 8];
      oacc = __builtin_amdgcn_mfma_f32_16x16x32_f16(pf, vf, oacc, 0, 0, 0);
      __syncthreads();
    }
  }
  lacc += __shfl_xor(lacc, 16, 64);
  lacc += __shfl_xor(lacc, 32, 64);
  #pragma unroll
  for (int r = 0; r < 4; r++) {
    float lr = __shfl(lacc, quad * 4 + r, 64);
    A[(base + row0 + quad * 4 + r) * 16 + col] = oacc[r] / lr;
  }
}

// ---------------- kernel 5: combine + wo + LN1 + FFN + LN2 + pool (fused) -----
__global__ __launch_bounds__(256) void k_combine_pool(
    const float* __restrict__ A, const float* __restrict__ x0,
    const float* __restrict__ wo, const float* __restrict__ bo,
    const float* __restrict__ w1, const float* __restrict__ b1,
    const float* __restrict__ w2, const float* __restrict__ b2,
    const float* __restrict__ g1, const float* __restrict__ bb1,
    const float* __restrict__ g2, const float* __restrict__ bb2,
    const float* __restrict__ wfc, const float* __restrict__ bfc,
    float* __restrict__ out) {
  __shared__ float swo[256], sw1[512], sw2[512];
  __shared__ float sbo[16], sb1[32], sb2[16], sg1[16], sbb1[16], sg2[16], sbb2[16];
  __shared__ float swf[16];
  int tid = threadIdx.x;
  swo[tid] = wo[tid];
  for (int i = tid; i < 512; i += 256) { sw1[i] = w1[i]; sw2[i] = w2[i]; }
  if (tid < 16) {
    sbo[tid] = bo[tid]; sb2[tid] = b2[tid];
    sg1[tid] = g1[tid]; sbb1[tid] = bb1[tid];
    sg2[tid] = g2[tid]; sbb2[tid] = bb2[tid];
    swf[tid] = wfc[tid];
  }
  if (tid < 32) sb1[tid] = b1[tid];
  __syncthreads();

  int idx = blockIdx.x * 256 + tid;          // [0, 81920)
  int bb = blockIdx.x / 5;
  const float* pa = A + (size_t)idx * 16;
  float a[16];
  #pragma unroll
  for (int d = 0; d < 16; d++) a[d] = pa[d];
  float h[16];
  const float* xr = x0 + (size_t)idx * 16;
  #pragma unroll
  for (int d = 0; d < 16; d++) {
    float o = sbo[d];
    #pragma unroll
    for (int e = 0; e < 16; e++) o += a[e] * swo[d * 16 + e];
    h[d] = xr[d] + o;
  }
  float mu = 0.f;
  #pragma unroll
  for (int d = 0; d < 16; d++) mu += h[d];
  mu *= (1.f / 16.f);
  float var = 0.f;
  #pragma unroll
  for (int d = 0; d < 16; d++) { float dd = h[d] - mu; var += dd * dd; }
  var *= (1.f / 16.f);
  float inv = 1.f / sqrtf(var + 1e-5f);
  float x1[16];
  #pragma unroll
  for (int d = 0; d < 16; d++) x1[d] = (h[d] - mu) * inv * sg1[d] + sbb1[d];
  float t1[32];
  #pragma unroll
  for (int j = 0; j < 32; j++) {
    float u = sb1[j];
    #pragma unroll
    for (int d = 0; d < 16; d++) u += x1[d] * sw1[j * 16 + d];
    t1[j] = fmaxf(u, 0.f);
  }
  float h2[16];
  #pragma unroll
  for (int d = 0; d < 16; d++) {
    float u = sb2[d];
    #pragma unroll
    for (int j = 0; j < 32; j++) u += t1[j] * sw2[d * 32 + j];
    h2[d] = x1[d] + u;
  }
  mu = 0.f;
  #pragma unroll
  for (int d = 0; d < 16; d++) mu += h2[d];
  mu *= (1.f / 16.f);
  var = 0.f;
  #pragma unroll
  for (int d = 0; d < 16; d++) { float dd = h2[d] - mu; var += dd * dd; }
  var *= (1.f / 16.f);
  inv = 1.f / sqrtf(var + 1e-5f);
  float pv = 0.f;
  #pragma unroll
  for (int d = 0; d < 16; d++)
    pv += ((h2[d] - mu) * inv * sg2[d] + sbb2[d]) * swf[d];
  double part = waveReduceSum((double)pv);
  __shared__ double red[4];
  int wid = tid >> 6, lane = tid & 63;
  if (lane == 0) red[wid] = part;
  __syncthreads();
  if (tid == 0) {
    double S = red[0] + red[1] + red[2] + red[3];
    float add = (float)(S / 1280.0);
    if (blockIdx.x % 5 == 0) add += bfc[0];
    atomicAdd(&out[bb], add);
  }
}

// ---------------- launch ------------------------------------------------------
extern "C" void kernel_launch(void* const* d_in, const int* in_sizes, int n_in,
                              void* d_out, int out_size, void* d_ws, size_t ws_size,
                              hipStream_t stream) {
  const float* x    = (const float*)d_in[0];
  const float* cw   = (const float*)d_in[1];
  const float* cb   = (const float*)d_in[2];
  const float* g0   = (const float*)d_in[3];
  const float* bt0  = (const float*)d_in[4];
  const float* wqkv = (const float*)d_in[5];
  const float* bqkv = (const float*)d_in[6];
  const float* wo   = (const float*)d_in[7];
  const float* bo   = (const float*)d_in[8];
  const float* w1   = (const float*)d_in[9];
  const float* b1   = (const float*)d_in[10];
  const float* w2   = (const float*)d_in[11];
  const float* b2   = (const float*)d_in[12];
  const float* g1   = (const float*)d_in[13];
  const float* bb1  = (const float*)d_in[14];
  const float* g2   = (const float*)d_in[15];
  const float* bb2  = (const float*)d_in[16];
  const float* wfc  = (const float*)d_in[17];
  const float* bfc  = (const float*)d_in[18];
  float* out = (float*)d_out;

  float* ws = (float*)d_ws;
  float* xs = ws;                       // 640*2000 = 1,280,000 (filtfilt output;
                                        // dead after k_resample_norm -> reused as A)
  float* y1 = xs + 1280000;             // spacer (dead)
  float* xn = y1 + 1306880;             // 640*1280   =   819,200
  float* x0 = xn + 819200;              // 64*1280*16 = 1,310,720
  float* Q  = x0 + 1310720;
  float* Kb = Q  + 1310720;
  float* Vb = Kb + 1310720;             // total ~36 MB
  float* Abuf = ws;                     // attention output (reuses dead xs)

  FiltArg fc; FirArg fa;
  build_filt(fc);
  design_fir(fa);

  k_filtfilt<<<640, 64, 0, stream>>>(x, xs, fc);
  k_resample_norm<<<640, 256, 0, stream>>>(xs, xn, fa);
  k_conv_ln_pe_qkv<<<320, 256, 0, stream>>>(xn, cw, cb, g0, bt0, wqkv, bqkv,
                                            x0, Q, Kb, Vb);
  k_attn_mfma<<<1280, 256, 0, stream>>>(Q, Kb, Vb, Abuf);
  hipMemsetAsync(out, 0, 64 * sizeof(float), stream);
  k_combine_pool<<<320, 256, 0, stream>>>(Abuf, x0, wo, bo, w1, b1, w2, b2,
                                          g1, bb1, g2, bb2, wfc, bfc, out);
}

// Round 8
// 279.403 us; speedup vs baseline: 1.7518x; 1.0768x over previous
//
#include <hip/hip_runtime.h>
#include <cmath>
#include <complex>
#include <algorithm>

#ifndef M_PI
#define M_PI 3.14159265358979323846
#endif

typedef _Float16 f16x8 __attribute__((ext_vector_type(8)));
typedef _Float16 f16x4 __attribute__((ext_vector_type(4)));
typedef float f32x4 __attribute__((ext_vector_type(4)));

// ---------------- coefficient structs (passed by value as kernel args) ---------
struct FiltArg {
  double b0[3], b1[3], b2[3], a1[3], a2[3];
  double zi0[3], zi1[3];
  double A32[36];              // (state-transition matrix)^32, 6x6 row-major
};
struct CorArg { double CA[32 * 6]; };  // CA[i][j] = output at step i from unit state e_j
struct FirArg { float h[526]; };  // 25 leading zeros + 501-tap kaiser-sinc, *UP

// ---------------- host-side filter design (exact replica of reference) --------
static void design_sos(FiltArg& sa) {
  const int order = 6;
  const double wn = 0.5 / 50.0;
  const double fs = 2.0;
  double warped = 2.0 * fs * std::tan(M_PI * wn / fs);
  std::complex<double> p[6];
  for (int i = 0; i < order; i++) {
    int m = -order + 1 + 2 * i;                      // -5,-3,-1,1,3,5
    p[i] = -std::exp(std::complex<double>(0.0, M_PI * m / (2.0 * order)));
  }
  std::complex<double> prod1(1, 0);
  for (int i = 0; i < 6; i++) prod1 *= -p[i];
  double k = (1.0 / prod1).real();
  for (int i = 0; i < 6; i++) p[i] = warped / p[i];
  const double fs2 = 2.0 * fs;
  std::complex<double> num(1, 0), den(1, 0);
  for (int i = 0; i < 6; i++) { num *= fs2; den *= (fs2 - p[i]); }
  k *= (num / den).real();
  for (int i = 0; i < 6; i++) p[i] = (fs2 + p[i]) / (fs2 - p[i]);
  std::complex<double> pp[3]; int n = 0;
  for (int i = 0; i < 6; i++) if (p[i].imag() > 0) pp[n++] = p[i];
  std::stable_sort(pp, pp + 3,
    [](const std::complex<double>& A, const std::complex<double>& B) {
      return std::fabs(std::abs(A) - 1.0) > std::fabs(std::abs(B) - 1.0);
    });
  double sos[3][6];
  for (int s = 0; s < 3; s++) {
    double g = (s == 0) ? k : 1.0;
    sos[s][0] = g; sos[s][1] = -2.0 * g; sos[s][2] = g;
    sos[s][3] = 1.0; sos[s][4] = -2.0 * pp[s].real(); sos[s][5] = std::norm(pp[s]);
  }
  double scale = 1.0;
  for (int s = 0; s < 3; s++) {
    double b0 = sos[s][0], b1 = sos[s][1], b2 = sos[s][2];
    double a1 = sos[s][4], a2 = sos[s][5];
    double det = 1.0 + a1 + a2;                      // det of [[1+a1,-1],[a2,1]]
    double r0 = b1 - a1 * b0, r1 = b2 - a2 * b0;
    double z0 = (r0 + r1) / det;
    double z1 = ((1.0 + a1) * r1 - a2 * r0) / det;
    sa.b0[s] = b0; sa.b1[s] = b1; sa.b2[s] = b2; sa.a1[s] = a1; sa.a2[s] = a2;
    sa.zi0[s] = scale * z0; sa.zi1[s] = scale * z1;
    scale *= (b0 + b1 + b2) / (1.0 + a1 + a2);
  }
}

static double host_step(const FiltArg& c, double z[6], double v) {
  for (int s = 0; s < 3; s++) {
    double y = c.b0[s] * v + z[2 * s];
    z[2 * s]     = c.b1[s] * v - c.a1[s] * y + z[2 * s + 1];
    z[2 * s + 1] = c.b2[s] * v - c.a2[s] * y;
    v = y;
  }
  return v;
}

static void build_filt(FiltArg& c, CorArg& co) {
  design_sos(c);
  double A[36];
  for (int j = 0; j < 6; j++) {
    double z[6] = {0, 0, 0, 0, 0, 0};
    z[j] = 1.0;
    host_step(c, z, 0.0);
    for (int i = 0; i < 6; i++) A[i * 6 + j] = z[i];
  }
  double M[36], T[36];
  for (int i = 0; i < 36; i++) M[i] = A[i];
  for (int sq = 0; sq < 5; sq++) {
    for (int i = 0; i < 6; i++)
      for (int j = 0; j < 6; j++) {
        double s = 0.0;
        for (int kk = 0; kk < 6; kk++) s += M[i * 6 + kk] * M[kk * 6 + j];
        T[i * 6 + j] = s;
      }
    for (int i = 0; i < 36; i++) M[i] = T[i];
  }
  for (int i = 0; i < 36; i++) c.A32[i] = M[i];
  // CA[i][j]: output at chunk-step i starting from unit state e_j, zero input
  for (int j = 0; j < 6; j++) {
    double z[6] = {0, 0, 0, 0, 0, 0};
    z[j] = 1.0;
    for (int i = 0; i < 32; i++) co.CA[i * 6 + j] = host_step(c, z, 0.0);
  }
}

static double bessel_i0(double x) {
  double s = 1.0, t = 1.0;
  for (int k = 1; k < 64; k++) {
    double u = x / (2.0 * k);
    t *= u * u; s += t;
    if (t < 1e-18 * s) break;
  }
  return s;
}

static void design_fir(FirArg& fa) {
  double h[501];
  const double fc = 1.0 / 25.0;
  double denom = bessel_i0(5.0);
  double sum = 0.0;
  for (int nn = 0; nn < 501; nn++) {
    double m = nn - 250.0;
    double xx = fc * m;
    double snc = (nn == 250) ? 1.0 : std::sin(M_PI * xx) / (M_PI * xx);
    double r = (2.0 * nn) / 500.0 - 1.0;
    double w = bessel_i0(5.0 * std::sqrt(std::max(0.0, 1.0 - r * r))) / denom;
    h[nn] = fc * snc * w; sum += h[nn];
  }
  for (int nn = 0; nn < 25; nn++) fa.h[nn] = 0.0f;          // n_pre_pad = 25
  for (int nn = 0; nn < 501; nn++) fa.h[25 + nn] = (float)(h[nn] / sum * 16.0);
}

// ---------------- device helpers ----------------
__device__ inline double waveReduceSum(double v) {
  #pragma unroll
  for (int off = 32; off > 0; off >>= 1) v += __shfl_down(v, off, 64);
  return v;
}

// ---------------- kernel 1: channel select + demean over 10 channels ---------
__global__ __launch_bounds__(256) void k_chansel(const float* __restrict__ x,
                                                 float* __restrict__ xs) {
  int idx = blockIdx.x * 256 + threadIdx.x;
  if (idx >= 64 * 2000) return;
  int b = idx / 2000, t = idx % 2000;
  const int ch[10] = {126, 125, 48, 112, 67, 93, 10, 61, 39, 108};
  const float* xb = x + (size_t)b * 128 * 2000;
  float v[10]; float s = 0.f;
  #pragma unroll
  for (int c = 0; c < 10; c++) { v[c] = xb[ch[c] * 2000 + t]; s += v[c]; }
  s *= 0.1f;
  #pragma unroll
  for (int c = 0; c < 10; c++) xs[((size_t)b * 10 + c) * 2000 + t] = v[c] - s;
}

// ---------------- kernel 2: filtfilt, register pass1 + parallel correction ----
// One block = one wave (64 threads) per row. Exact linear decomposition:
//   y_true[i] = y_zerostate[i] + CA[i].z_start  (CA = C*A^i, host-precomputed)
// so the serial replay pass is replaced by a parallel 6-FMA correction.
// The 64-chunk affine scan runs on 6 lanes (lane i = state component i) with
// __shfl broadcast -- ~6 dependent FMAs per iteration instead of 36.
// LDS padded: XR/YF chunk stride 33 (conflict-free / b64 floor), Fs/Zs [64][7].
#define XR(t) xr[(t) + ((t) >> 5)]
#define YF(t) yf[(t) + ((t) >> 5)]
__global__ __launch_bounds__(64) void k_filtfilt(float* __restrict__ xs,
                                                 FiltArg c, CorArg co) {
  __shared__ float xr[2112];      // extended input seq (padded)
  __shared__ double yf[2112];     // corrected forward output (padded)
  __shared__ double Fs[64][7];
  __shared__ double Zs[64][7];
  int r = blockIdx.x;
  int k = threadIdx.x;
  float* x = xs + (size_t)r * 2000;

  // stage extended (reflected) sequence once; branch logic leaves the hot loop
  float x0f = x[0], xlf = x[1999];
  for (int t = k; t < 2048; t += 64) {
    float v;
    if (t < 21)        v = 2.f * x0f - x[21 - t];
    else if (t < 2021) v = x[t - 21];
    else if (t < 2042) v = 2.f * xlf - x[4019 - t];
    else               v = 0.f;
    XR(t) = v;
  }
  __syncthreads();

  double b0[3], b1[3], b2[3], a1[3], a2[3];
  #pragma unroll
  for (int s = 0; s < 3; s++) {
    b0[s] = c.b0[s]; b1[s] = c.b1[s]; b2[s] = c.b2[s];
    a1[s] = c.a1[s]; a2[s] = c.a2[s];
  }
  auto step = [&](double* z, double v) -> double {
    #pragma unroll
    for (int s = 0; s < 3; s++) {
      double y = b0[s] * v + z[2 * s];
      z[2 * s]     = b1[s] * v - a1[s] * y + z[2 * s + 1];
      z[2 * s + 1] = b2[s] * v - a2[s] * y;
      v = y;
    }
    return v;
  };
  // 6-lane affine scan: lane i carries state component i across 64 chunks
  double arow[6] = {0, 0, 0, 0, 0, 0};
  if (k < 6) {
    #pragma unroll
    for (int j = 0; j < 6; j++) arow[j] = c.A32[k * 6 + j];
  }
  int li = (k < 6) ? k : 0;
  auto scan = [&](double seed) {
    double zz = 0.0;
    if (k < 6) zz = ((k & 1) ? c.zi1[k >> 1] : c.zi0[k >> 1]) * seed;
    for (int kk = 0; kk < 64; kk++) {
      if (k < 6) Zs[kk][k] = zz;
      double f = Fs[kk][li];
      double nz = f;
      #pragma unroll
      for (int j = 0; j < 6; j++) nz += arow[j] * __shfl(zz, j, 64);
      zz = nz;
    }
  };

  int t0 = k * 32;
  double z[6], yreg[32];

  // ---- forward: zero-state pass (outputs kept in registers) ----
  #pragma unroll
  for (int i = 0; i < 6; i++) z[i] = 0.0;
  for (int i = 0; i < 32; i++) yreg[i] = step(z, (double)XR(t0 + i));
  #pragma unroll
  for (int i = 0; i < 6; i++) Fs[k][i] = z[i];
  __syncthreads();
  scan((double)XR(0));
  __syncthreads();
  // ---- forward correction: y_true = y_zero + CA[i].z_start (parallel) ----
  #pragma unroll
  for (int i = 0; i < 6; i++) z[i] = Zs[k][i];
  for (int i = 0; i < 32; i++) {
    double corr = 0.0;
    #pragma unroll
    for (int j = 0; j < 6; j++) corr += co.CA[i * 6 + j] * z[j];
    YF(t0 + i) = yreg[i] + corr;
  }
  __syncthreads();

  // ---- backward over reversed yf ----
  auto rin = [&](int j) -> double { return (j <= 2041) ? YF(2041 - j) : 0.0; };
  #pragma unroll
  for (int i = 0; i < 6; i++) z[i] = 0.0;
  for (int i = 0; i < 32; i++) yreg[i] = step(z, rin(t0 + i));
  #pragma unroll
  for (int i = 0; i < 6; i++) Fs[k][i] = z[i];
  __syncthreads();
  scan(YF(2041));
  __syncthreads();
  #pragma unroll
  for (int i = 0; i < 6; i++) z[i] = Zs[k][i];
  for (int i = 0; i < 32; i++) {
    int j = t0 + i;
    if (j >= 21 && j <= 2020) {
      double corr = 0.0;
      #pragma unroll
      for (int jj = 0; jj < 6; jj++) corr += co.CA[i * 6 + jj] * z[jj];
      x[2020 - j] = (float)(yreg[i] + corr);   // reversed + trimmed
    }
  }
}

// ---------------- kernel 3: polyphase resample + tanh + per-row normalize ----
__global__ __launch_bounds__(256) void k_resample_norm(const float* __restrict__ xf,
                                                       float* __restrict__ xn,
                                                       FirArg fa) {
  __shared__ float xl[2000];
  __shared__ float hl[526];
  int r = blockIdx.x;                         // 640 rows
  const float* x = xf + (size_t)r * 2000;
  for (int i = threadIdx.x; i < 2000; i += 256) xl[i] = x[i];
  for (int i = threadIdx.x; i < 526; i += 256) hl[i] = fa.h[i];
  __syncthreads();
  float vals[5];
  #pragma unroll
  for (int kk = 0; kk < 5; kk++) {
    int o = threadIdx.x + kk * 256;           // 1280 outputs per row
    int P = 25 * (o + 11);
    int phase = P & 15;
    float acc = 0.f;
    for (int m = phase; m <= 525; m += 16) {
      int idx = (P - m) >> 4;
      if (idx >= 0 && idx < 2000) acc += hl[m] * xl[idx];
    }
    vals[kk] = tanhf(acc);
  }
  double s = 0.0, ss = 0.0;
  #pragma unroll
  for (int kk = 0; kk < 5; kk++) {
    s += (double)vals[kk]; ss += (double)vals[kk] * (double)vals[kk];
  }
  s = waveReduceSum(s); ss = waveReduceSum(ss);
  __shared__ double red[8];
  int wid = threadIdx.x >> 6, lane = threadIdx.x & 63;
  if (lane == 0) { red[wid] = s; red[4 + wid] = ss; }
  __syncthreads();
  double S = red[0] + red[1] + red[2] + red[3];
  double SS = red[4] + red[5] + red[6] + red[7];
  double mean = S / 1280.0;
  double var = (SS - 1280.0 * mean * mean) / 1279.0;
  double sd = fmax(sqrt(fmax(var, 0.0)), 1e-6);
  float fmean = (float)mean, finv = (float)(1.0 / sd);
  #pragma unroll
  for (int kk = 0; kk < 5; kk++)
    xn[(size_t)r * 1280 + threadIdx.x + kk * 256] = (vals[kk] - fmean) * finv;
}

// ---------------- kernel 4: conv1d + relu + LN + PE(inline) + QKV (fused) -----
__global__ __launch_bounds__(256) void k_conv_ln_pe_qkv(const float* __restrict__ xn,
    const float* __restrict__ cw, const float* __restrict__ cb,
    const float* __restrict__ g0, const float* __restrict__ bt0,
    const float* __restrict__ wqkv, const float* __restrict__ bqkv,
    float* __restrict__ x0,
    float* __restrict__ Q, float* __restrict__ K, float* __restrict__ V) {
  __shared__ float w[480], bias[16], gg[16], gb[16];
  __shared__ float wq[768], bq[48];
  for (int i = threadIdx.x; i < 480; i += 256) w[i] = cw[i];
  for (int i = threadIdx.x; i < 768; i += 256) wq[i] = wqkv[i];
  if (threadIdx.x < 16) {
    bias[threadIdx.x] = cb[threadIdx.x];
    gg[threadIdx.x] = g0[threadIdx.x];
    gb[threadIdx.x] = bt0[threadIdx.x];
  }
  if (threadIdx.x < 48) bq[threadIdx.x] = bqkv[threadIdx.x];
  __syncthreads();
  int idx = blockIdx.x * 256 + threadIdx.x;
  int b = idx / 1280, t = idx % 1280;
  const float* xb = xn + (size_t)b * 10 * 1280;
  float in[10][3];
  #pragma unroll
  for (int i = 0; i < 10; i++)
    #pragma unroll
    for (int k = 0; k < 3; k++) {
      int tt = t - 1 + k;
      in[i][k] = (tt >= 0 && tt < 1280) ? xb[i * 1280 + tt] : 0.f;
    }
  float o[16];
  #pragma unroll
  for (int oc = 0; oc < 16; oc++) {
    float a = bias[oc];
    #pragma unroll
    for (int i = 0; i < 10; i++)
      #pragma unroll
      for (int k = 0; k < 3; k++) a += in[i][k] * w[oc * 30 + i * 3 + k];
    o[oc] = fmaxf(a, 0.f);
  }
  float mu = 0.f;
  #pragma unroll
  for (int d = 0; d < 16; d++) mu += o[d];
  mu *= (1.f / 16.f);
  float var = 0.f;
  #pragma unroll
  for (int d = 0; d < 16; d++) { float dd = o[d] - mu; var += dd * dd; }
  var *= (1.f / 16.f);
  float inv = 1.f / sqrtf(var + 1e-5f);
  float xv[16];
  float* outp = x0 + (size_t)idx * 16;
  #pragma unroll
  for (int d = 0; d < 16; d++) {
    int j = d >> 1;
    double dv = exp(-((double)(2 * j)) * 0.5756462732485114); // ln(10000)/16
    double ang = (double)t * dv;
    float pe = (float)((d & 1) ? cos(ang) : sin(ang));
    xv[d] = (o[d] - mu) * inv * gg[d] + gb[d] + pe;
    outp[d] = xv[d];
  }
  float* qp = Q + (size_t)idx * 16;
  float* kp = K + (size_t)idx * 16;
  float* vp = V + (size_t)idx * 16;
  #pragma unroll
  for (int j = 0; j < 16; j++) {
    float a = bq[j];
    #pragma unroll
    for (int d = 0; d < 16; d++) a += xv[d] * wq[j * 16 + d];
    qp[j] = a;
  }
  #pragma unroll
  for (int j = 0; j < 16; j++) {
    float a = bq[16 + j];
    #pragma unroll
    for (int d = 0; d < 16; d++) a += xv[d] * wq[(16 + j) * 16 + d];
    kp[j] = a;
  }
  #pragma unroll
  for (int j = 0; j < 16; j++) {
    float a = bq[32 + j];
    #pragma unroll
    for (int d = 0; d < 16; d++) a += xv[d] * wq[(32 + j) * 16 + d];
    vp[j] = a;
  }
}

// ---------------- kernel 5: MFMA attention ------------------------------------
#define ATT_SHIFT 12.0f
__global__ __launch_bounds__(256) void k_attn_mfma(const float* __restrict__ Q,
    const float* __restrict__ K, const float* __restrict__ V,
    float* __restrict__ A) {
  __shared__ __align__(16) _Float16 Ks[64 * 40];   // [key][d], d 16..31 zero
  __shared__ __align__(16) _Float16 Vt[16 * 72];   // [d][key]
  __shared__ __align__(16) _Float16 Pld[4][16 * 40]; // per-wave [qrow][key32]
  int tid = threadIdx.x;
  int b  = blockIdx.x / 20;
  int rg = blockIdx.x % 20;
  int wv = tid >> 6;
  int lane = tid & 63;
  int col = lane & 15;
  int quad = lane >> 4;
  size_t base = (size_t)b * 1280;
  int row0 = rg * 64 + wv * 16;

  f16x8 qf;
  #pragma unroll
  for (int j = 0; j < 8; j++) qf[j] = (_Float16)0.f;
  if (quad < 2) {
    const float* qp = Q + (base + row0 + col) * 16 + quad * 8;
    #pragma unroll
    for (int j = 0; j < 8; j++) qf[j] = (_Float16)(0.25f * qp[j]);
  }
  f32x4 oacc = {0.f, 0.f, 0.f, 0.f};
  float lacc = 0.f;

  for (int s = 0; s < 20; s++) {
    __syncthreads();
    {
      int key = tid >> 2, part = tid & 3;
      const float* kp = K + (base + s * 64 + key) * 16 + part * 4;
      f16x4 hk, hz;
      #pragma unroll
      for (int j = 0; j < 4; j++) { hk[j] = (_Float16)kp[j]; hz[j] = (_Float16)0.f; }
      *(f16x4*)&Ks[key * 40 + part * 4] = hk;
      *(f16x4*)&Ks[key * 40 + 16 + part * 4] = hz;
      const float* vp = V + (base + s * 64 + key) * 16 + part * 4;
      #pragma unroll
      for (int j = 0; j < 4; j++) Vt[(part * 4 + j) * 72 + key] = (_Float16)vp[j];
    }
    __syncthreads();
    #pragma unroll
    for (int c = 0; c < 2; c++) {
      #pragma unroll
      for (int t = 0; t < 2; t++) {
        int keyoff = c * 32 + t * 16;
        f16x8 af = *(f16x8*)&Ks[(keyoff + col) * 40 + quad * 8];
        f32x4 sf = {0.f, 0.f, 0.f, 0.f};
        sf = __builtin_amdgcn_mfma_f32_16x16x32_f16(af, qf, sf, 0, 0, 0);
        f16x4 ph;
        float psum = 0.f;
        #pragma unroll
        for (int r = 0; r < 4; r++) {
          float p = __expf(sf[r] - ATT_SHIFT);
          psum += p;
          ph[r] = (_Float16)p;
        }
        lacc += psum;
        *(f16x4*)&Pld[wv][col * 40 + t * 16 + quad * 4] = ph;
      }
      __syncthreads();
      f16x8 pf = *(f16x8*)&Pld[wv][col * 40 + quad * 8];
      f16x8 vf = *(f16x8*)&Vt[col * 72 + c * 32 + quad * 8];
      oacc = __builtin_amdgcn_mfma_f32_16x16x32_f16(pf, vf, oacc, 0, 0, 0);
      __syncthreads();
    }
  }
  lacc += __shfl_xor(lacc, 16, 64);
  lacc += __shfl_xor(lacc, 32, 64);
  #pragma unroll
  for (int r = 0; r < 4; r++) {
    float lr = __shfl(lacc, quad * 4 + r, 64);
    A[(base + row0 + quad * 4 + r) * 16 + col] = oacc[r] / lr;
  }
}

// ---------------- kernel 6: combine + wo + LN1 + FFN + LN2 + pool (fused) -----
__global__ __launch_bounds__(256) void k_combine_pool(
    const float* __restrict__ A, const float* __restrict__ x0,
    const float* __restrict__ wo, const float* __restrict__ bo,
    const float* __restrict__ w1, const float* __restrict__ b1,
    const float* __restrict__ w2, const float* __restrict__ b2,
    const float* __restrict__ g1, const float* __restrict__ bb1,
    const float* __restrict__ g2, const float* __restrict__ bb2,
    const float* __restrict__ wfc, const float* __restrict__ bfc,
    float* __restrict__ out) {
  __shared__ float swo[256], sw1[512], sw2[512];
  __shared__ float sbo[16], sb1[32], sb2[16], sg1[16], sbb1[16], sg2[16], sbb2[16];
  __shared__ float swf[16];
  int tid = threadIdx.x;
  swo[tid] = wo[tid];
  for (int i = tid; i < 512; i += 256) { sw1[i] = w1[i]; sw2[i] = w2[i]; }
  if (tid < 16) {
    sbo[tid] = bo[tid]; sb2[tid] = b2[tid];
    sg1[tid] = g1[tid]; sbb1[tid] = bb1[tid];
    sg2[tid] = g2[tid]; sbb2[tid] = bb2[tid];
    swf[tid] = wfc[tid];
  }
  if (tid < 32) sb1[tid] = b1[tid];
  __syncthreads();

  int idx = blockIdx.x * 256 + tid;          // [0, 81920)
  int bb = blockIdx.x / 5;
  const float* pa = A + (size_t)idx * 16;
  float a[16];
  #pragma unroll
  for (int d = 0; d < 16; d++) a[d] = pa[d];
  float h[16];
  const float* xr = x0 + (size_t)idx * 16;
  #pragma unroll
  for (int d = 0; d < 16; d++) {
    float o = sbo[d];
    #pragma unroll
    for (int e = 0; e < 16; e++) o += a[e] * swo[d * 16 + e];
    h[d] = xr[d] + o;
  }
  float mu = 0.f;
  #pragma unroll
  for (int d = 0; d < 16; d++) mu += h[d];
  mu *= (1.f / 16.f);
  float var = 0.f;
  #pragma unroll
  for (int d = 0; d < 16; d++) { float dd = h[d] - mu; var += dd * dd; }
  var *= (1.f / 16.f);
  float inv = 1.f / sqrtf(var + 1e-5f);
  float x1[16];
  #pragma unroll
  for (int d = 0; d < 16; d++) x1[d] = (h[d] - mu) * inv * sg1[d] + sbb1[d];
  float t1[32];
  #pragma unroll
  for (int j = 0; j < 32; j++) {
    float u = sb1[j];
    #pragma unroll
    for (int d = 0; d < 16; d++) u += x1[d] * sw1[j * 16 + d];
    t1[j] = fmaxf(u, 0.f);
  }
  float h2[16];
  #pragma unroll
  for (int d = 0; d < 16; d++) {
    float u = sb2[d];
    #pragma unroll
    for (int j = 0; j < 32; j++) u += t1[j] * sw2[d * 32 + j];
    h2[d] = x1[d] + u;
  }
  mu = 0.f;
  #pragma unroll
  for (int d = 0; d < 16; d++) mu += h2[d];
  mu *= (1.f / 16.f);
  var = 0.f;
  #pragma unroll
  for (int d = 0; d < 16; d++) { float dd = h2[d] - mu; var += dd * dd; }
  var *= (1.f / 16.f);
  inv = 1.f / sqrtf(var + 1e-5f);
  float pv = 0.f;
  #pragma unroll
  for (int d = 0; d < 16; d++)
    pv += ((h2[d] - mu) * inv * sg2[d] + sbb2[d]) * swf[d];
  double part = waveReduceSum((double)pv);
  __shared__ double red[4];
  int wid = tid >> 6, lane = tid & 63;
  if (lane == 0) red[wid] = part;
  __syncthreads();
  if (tid == 0) {
    double S = red[0] + red[1] + red[2] + red[3];
    float add = (float)(S / 1280.0);
    if (blockIdx.x % 5 == 0) add += bfc[0];
    atomicAdd(&out[bb], add);
  }
}

// ---------------- launch ------------------------------------------------------
extern "C" void kernel_launch(void* const* d_in, const int* in_sizes, int n_in,
                              void* d_out, int out_size, void* d_ws, size_t ws_size,
                              hipStream_t stream) {
  const float* x    = (const float*)d_in[0];
  const float* cw   = (const float*)d_in[1];
  const float* cb   = (const float*)d_in[2];
  const float* g0   = (const float*)d_in[3];
  const float* bt0  = (const float*)d_in[4];
  const float* wqkv = (const float*)d_in[5];
  const float* bqkv = (const float*)d_in[6];
  const float* wo   = (const float*)d_in[7];
  const float* bo   = (const float*)d_in[8];
  const float* w1   = (const float*)d_in[9];
  const float* b1   = (const float*)d_in[10];
  const float* w2   = (const float*)d_in[11];
  const float* b2   = (const float*)d_in[12];
  const float* g1   = (const float*)d_in[13];
  const float* bb1  = (const float*)d_in[14];
  const float* g2   = (const float*)d_in[15];
  const float* bb2  = (const float*)d_in[16];
  const float* wfc  = (const float*)d_in[17];
  const float* bfc  = (const float*)d_in[18];
  float* out = (float*)d_out;

  float* ws = (float*)d_ws;
  float* xs = ws;                       // 640*2000 = 1,280,000 (filtered in-place;
                                        // dead after k_resample_norm -> reused as A)
  float* y1 = xs + 1280000;             // spacer (dead)
  float* xn = y1 + 1306880;             // 640*1280   =   819,200
  float* x0 = xn + 819200;              // 64*1280*16 = 1,310,720
  float* Q  = x0 + 1310720;
  float* Kb = Q  + 1310720;
  float* Vb = Kb + 1310720;             // total ~36 MB
  float* Abuf = ws;                     // attention output (reuses dead xs)

  FiltArg fc; CorArg co; FirArg fa;
  build_filt(fc, co);
  design_fir(fa);

  k_chansel<<<(64 * 2000 + 255) / 256, 256, 0, stream>>>(x, xs);
  k_filtfilt<<<640, 64, 0, stream>>>(xs, fc, co);
  k_resample_norm<<<640, 256, 0, stream>>>(xs, xn, fa);
  k_conv_ln_pe_qkv<<<320, 256, 0, stream>>>(xn, cw, cb, g0, bt0, wqkv, bqkv,
                                            x0, Q, Kb, Vb);
  k_attn_mfma<<<1280, 256, 0, stream>>>(Q, Kb, Vb, Abuf);
  hipMemsetAsync(out, 0, 64 * sizeof(float), stream);
  k_combine_pool<<<320, 256, 0, stream>>>(Abuf, x0, wo, bo, w1, b1, w2, b2,
                                          g1, bb1, g2, bb2, wfc, bfc, out);
}

// Round 9
// 257.382 us; speedup vs baseline: 1.9016x; 1.0856x over previous
//
#include <hip/hip_runtime.h>
#include <cmath>
#include <complex>
#include <algorithm>

#ifndef M_PI
#define M_PI 3.14159265358979323846
#endif

typedef _Float16 f16x8 __attribute__((ext_vector_type(8)));
typedef _Float16 f16x4 __attribute__((ext_vector_type(4)));
typedef float f32x4 __attribute__((ext_vector_type(4)));

// ---------------- coefficient structs (passed by value as kernel args) ---------
struct FiltArg {
  double b0[3], b1[3], b2[3], a1[3], a2[3];
  double zi0[3], zi1[3];
  double A32[36];              // (state-transition matrix)^32, 6x6 row-major
};
struct CorArg { double CA[32 * 6]; };  // CA[i][j] = output at step i from unit state e_j
struct FirArg { float h[526]; };  // 25 leading zeros + 501-tap kaiser-sinc, *UP

// ---------------- host-side filter design (exact replica of reference) --------
static void design_sos(FiltArg& sa) {
  const int order = 6;
  const double wn = 0.5 / 50.0;
  const double fs = 2.0;
  double warped = 2.0 * fs * std::tan(M_PI * wn / fs);
  std::complex<double> p[6];
  for (int i = 0; i < order; i++) {
    int m = -order + 1 + 2 * i;                      // -5,-3,-1,1,3,5
    p[i] = -std::exp(std::complex<double>(0.0, M_PI * m / (2.0 * order)));
  }
  std::complex<double> prod1(1, 0);
  for (int i = 0; i < 6; i++) prod1 *= -p[i];
  double k = (1.0 / prod1).real();
  for (int i = 0; i < 6; i++) p[i] = warped / p[i];
  const double fs2 = 2.0 * fs;
  std::complex<double> num(1, 0), den(1, 0);
  for (int i = 0; i < 6; i++) { num *= fs2; den *= (fs2 - p[i]); }
  k *= (num / den).real();
  for (int i = 0; i < 6; i++) p[i] = (fs2 + p[i]) / (fs2 - p[i]);
  std::complex<double> pp[3]; int n = 0;
  for (int i = 0; i < 6; i++) if (p[i].imag() > 0) pp[n++] = p[i];
  std::stable_sort(pp, pp + 3,
    [](const std::complex<double>& A, const std::complex<double>& B) {
      return std::fabs(std::abs(A) - 1.0) > std::fabs(std::abs(B) - 1.0);
    });
  double sos[3][6];
  for (int s = 0; s < 3; s++) {
    double g = (s == 0) ? k : 1.0;
    sos[s][0] = g; sos[s][1] = -2.0 * g; sos[s][2] = g;
    sos[s][3] = 1.0; sos[s][4] = -2.0 * pp[s].real(); sos[s][5] = std::norm(pp[s]);
  }
  double scale = 1.0;
  for (int s = 0; s < 3; s++) {
    double b0 = sos[s][0], b1 = sos[s][1], b2 = sos[s][2];
    double a1 = sos[s][4], a2 = sos[s][5];
    double det = 1.0 + a1 + a2;                      // det of [[1+a1,-1],[a2,1]]
    double r0 = b1 - a1 * b0, r1 = b2 - a2 * b0;
    double z0 = (r0 + r1) / det;
    double z1 = ((1.0 + a1) * r1 - a2 * r0) / det;
    sa.b0[s] = b0; sa.b1[s] = b1; sa.b2[s] = b2; sa.a1[s] = a1; sa.a2[s] = a2;
    sa.zi0[s] = scale * z0; sa.zi1[s] = scale * z1;
    scale *= (b0 + b1 + b2) / (1.0 + a1 + a2);
  }
}

static double host_step(const FiltArg& c, double z[6], double v) {
  for (int s = 0; s < 3; s++) {
    double y = c.b0[s] * v + z[2 * s];
    z[2 * s]     = c.b1[s] * v - c.a1[s] * y + z[2 * s + 1];
    z[2 * s + 1] = c.b2[s] * v - c.a2[s] * y;
    v = y;
  }
  return v;
}

static void build_filt(FiltArg& c, CorArg& co) {
  design_sos(c);
  double A[36];
  for (int j = 0; j < 6; j++) {
    double z[6] = {0, 0, 0, 0, 0, 0};
    z[j] = 1.0;
    host_step(c, z, 0.0);
    for (int i = 0; i < 6; i++) A[i * 6 + j] = z[i];
  }
  double M[36], T[36];
  for (int i = 0; i < 36; i++) M[i] = A[i];
  for (int sq = 0; sq < 5; sq++) {
    for (int i = 0; i < 6; i++)
      for (int j = 0; j < 6; j++) {
        double s = 0.0;
        for (int kk = 0; kk < 6; kk++) s += M[i * 6 + kk] * M[kk * 6 + j];
        T[i * 6 + j] = s;
      }
    for (int i = 0; i < 36; i++) M[i] = T[i];
  }
  for (int i = 0; i < 36; i++) c.A32[i] = M[i];
  // CA[i][j]: output at chunk-step i starting from unit state e_j, zero input
  for (int j = 0; j < 6; j++) {
    double z[6] = {0, 0, 0, 0, 0, 0};
    z[j] = 1.0;
    for (int i = 0; i < 32; i++) co.CA[i * 6 + j] = host_step(c, z, 0.0);
  }
}

static double bessel_i0(double x) {
  double s = 1.0, t = 1.0;
  for (int k = 1; k < 64; k++) {
    double u = x / (2.0 * k);
    t *= u * u; s += t;
    if (t < 1e-18 * s) break;
  }
  return s;
}

static void design_fir(FirArg& fa) {
  double h[501];
  const double fc = 1.0 / 25.0;
  double denom = bessel_i0(5.0);
  double sum = 0.0;
  for (int nn = 0; nn < 501; nn++) {
    double m = nn - 250.0;
    double xx = fc * m;
    double snc = (nn == 250) ? 1.0 : std::sin(M_PI * xx) / (M_PI * xx);
    double r = (2.0 * nn) / 500.0 - 1.0;
    double w = bessel_i0(5.0 * std::sqrt(std::max(0.0, 1.0 - r * r))) / denom;
    h[nn] = fc * snc * w; sum += h[nn];
  }
  for (int nn = 0; nn < 25; nn++) fa.h[nn] = 0.0f;          // n_pre_pad = 25
  for (int nn = 0; nn < 501; nn++) fa.h[25 + nn] = (float)(h[nn] / sum * 16.0);
}

// ---------------- device helpers ----------------
__device__ inline double waveReduceSum(double v) {
  #pragma unroll
  for (int off = 32; off > 0; off >>= 1) v += __shfl_down(v, off, 64);
  return v;
}

// ---------------- kernel 1: channel select + demean over 10 channels ---------
__global__ __launch_bounds__(256) void k_chansel(const float* __restrict__ x,
                                                 float* __restrict__ xs) {
  int idx = blockIdx.x * 256 + threadIdx.x;
  if (idx >= 64 * 2000) return;
  int b = idx / 2000, t = idx % 2000;
  const int ch[10] = {126, 125, 48, 112, 67, 93, 10, 61, 39, 108};
  const float* xb = x + (size_t)b * 128 * 2000;
  float v[10]; float s = 0.f;
  #pragma unroll
  for (int c = 0; c < 10; c++) { v[c] = xb[ch[c] * 2000 + t]; s += v[c]; }
  s *= 0.1f;
  #pragma unroll
  for (int c = 0; c < 10; c++) xs[((size_t)b * 10 + c) * 2000 + t] = v[c] - s;
}

// ---------------- kernel 2: filtfilt, register pass1 + parallel correction ----
#define XR(t) xr[(t) + ((t) >> 5)]
#define YF(t) yf[(t) + ((t) >> 5)]
__global__ __launch_bounds__(64) void k_filtfilt(float* __restrict__ xs,
                                                 FiltArg c, CorArg co) {
  __shared__ float xr[2112];      // extended input seq (padded)
  __shared__ double yf[2112];     // corrected forward output (padded)
  __shared__ double Fs[64][7];
  __shared__ double Zs[64][7];
  int r = blockIdx.x;
  int k = threadIdx.x;
  float* x = xs + (size_t)r * 2000;

  float x0f = x[0], xlf = x[1999];
  for (int t = k; t < 2048; t += 64) {
    float v;
    if (t < 21)        v = 2.f * x0f - x[21 - t];
    else if (t < 2021) v = x[t - 21];
    else if (t < 2042) v = 2.f * xlf - x[4019 - t];
    else               v = 0.f;
    XR(t) = v;
  }
  __syncthreads();

  double b0[3], b1[3], b2[3], a1[3], a2[3];
  #pragma unroll
  for (int s = 0; s < 3; s++) {
    b0[s] = c.b0[s]; b1[s] = c.b1[s]; b2[s] = c.b2[s];
    a1[s] = c.a1[s]; a2[s] = c.a2[s];
  }
  auto step = [&](double* z, double v) -> double {
    #pragma unroll
    for (int s = 0; s < 3; s++) {
      double y = b0[s] * v + z[2 * s];
      z[2 * s]     = b1[s] * v - a1[s] * y + z[2 * s + 1];
      z[2 * s + 1] = b2[s] * v - a2[s] * y;
      v = y;
    }
    return v;
  };
  double arow[6] = {0, 0, 0, 0, 0, 0};
  if (k < 6) {
    #pragma unroll
    for (int j = 0; j < 6; j++) arow[j] = c.A32[k * 6 + j];
  }
  int li = (k < 6) ? k : 0;
  auto scan = [&](double seed) {
    double zz = 0.0;
    if (k < 6) zz = ((k & 1) ? c.zi1[k >> 1] : c.zi0[k >> 1]) * seed;
    for (int kk = 0; kk < 64; kk++) {
      if (k < 6) Zs[kk][k] = zz;
      double f = Fs[kk][li];
      double nz = f;
      #pragma unroll
      for (int j = 0; j < 6; j++) nz += arow[j] * __shfl(zz, j, 64);
      zz = nz;
    }
  };

  int t0 = k * 32;
  double z[6], yreg[32];

  #pragma unroll
  for (int i = 0; i < 6; i++) z[i] = 0.0;
  for (int i = 0; i < 32; i++) yreg[i] = step(z, (double)XR(t0 + i));
  #pragma unroll
  for (int i = 0; i < 6; i++) Fs[k][i] = z[i];
  __syncthreads();
  scan((double)XR(0));
  __syncthreads();
  #pragma unroll
  for (int i = 0; i < 6; i++) z[i] = Zs[k][i];
  for (int i = 0; i < 32; i++) {
    double corr = 0.0;
    #pragma unroll
    for (int j = 0; j < 6; j++) corr += co.CA[i * 6 + j] * z[j];
    YF(t0 + i) = yreg[i] + corr;
  }
  __syncthreads();

  auto rin = [&](int j) -> double { return (j <= 2041) ? YF(2041 - j) : 0.0; };
  #pragma unroll
  for (int i = 0; i < 6; i++) z[i] = 0.0;
  for (int i = 0; i < 32; i++) yreg[i] = step(z, rin(t0 + i));
  #pragma unroll
  for (int i = 0; i < 6; i++) Fs[k][i] = z[i];
  __syncthreads();
  scan(YF(2041));
  __syncthreads();
  #pragma unroll
  for (int i = 0; i < 6; i++) z[i] = Zs[k][i];
  for (int i = 0; i < 32; i++) {
    int j = t0 + i;
    if (j >= 21 && j <= 2020) {
      double corr = 0.0;
      #pragma unroll
      for (int jj = 0; jj < 6; jj++) corr += co.CA[i * 6 + jj] * z[jj];
      x[2020 - j] = (float)(yreg[i] + corr);   // reversed + trimmed
    }
  }
}

// ---------------- kernel 3: PE table (f64 trig, separate so conv stays lean) --
__global__ __launch_bounds__(256) void k_pe(float* __restrict__ pe) {
  int i = blockIdx.x * 256 + threadIdx.x;
  if (i >= 1280 * 16) return;
  int t = i >> 4, d = i & 15, j = d >> 1;
  double div = exp(-((double)(2 * j)) * 0.5756462732485114); // ln(10000)/16
  double a = (double)t * div;
  pe[i] = (float)((d & 1) ? cos(a) : sin(a));
}

// ---------------- kernel 4: polyphase resample + tanh + per-row normalize ----
__global__ __launch_bounds__(256) void k_resample_norm(const float* __restrict__ xf,
                                                       float* __restrict__ xn,
                                                       FirArg fa) {
  __shared__ float xl[2000];
  __shared__ float hl[526];
  int r = blockIdx.x;                         // 640 rows
  const float* x = xf + (size_t)r * 2000;
  for (int i = threadIdx.x; i < 2000; i += 256) xl[i] = x[i];
  for (int i = threadIdx.x; i < 526; i += 256) hl[i] = fa.h[i];
  __syncthreads();
  float vals[5];
  #pragma unroll
  for (int kk = 0; kk < 5; kk++) {
    int o = threadIdx.x + kk * 256;           // 1280 outputs per row
    int P = 25 * (o + 11);
    int phase = P & 15;
    float acc = 0.f;
    for (int m = phase; m <= 525; m += 16) {
      int idx = (P - m) >> 4;
      if (idx >= 0 && idx < 2000) acc += hl[m] * xl[idx];
    }
    vals[kk] = tanhf(acc);
  }
  double s = 0.0, ss = 0.0;
  #pragma unroll
  for (int kk = 0; kk < 5; kk++) {
    s += (double)vals[kk]; ss += (double)vals[kk] * (double)vals[kk];
  }
  s = waveReduceSum(s); ss = waveReduceSum(ss);
  __shared__ double red[8];
  int wid = threadIdx.x >> 6, lane = threadIdx.x & 63;
  if (lane == 0) { red[wid] = s; red[4 + wid] = ss; }
  __syncthreads();
  double S = red[0] + red[1] + red[2] + red[3];
  double SS = red[4] + red[5] + red[6] + red[7];
  double mean = S / 1280.0;
  double var = (SS - 1280.0 * mean * mean) / 1279.0;
  double sd = fmax(sqrt(fmax(var, 0.0)), 1e-6);
  float fmean = (float)mean, finv = (float)(1.0 / sd);
  #pragma unroll
  for (int kk = 0; kk < 5; kk++)
    xn[(size_t)r * 1280 + threadIdx.x + kk * 256] = (vals[kk] - fmean) * finv;
}

// ---------------- kernel 5: conv1d + relu + LN + PE(table) + QKV (fused) ------
// PE from precomputed table (k_pe) -- keeps f64 transcendentals out of this
// kernel (round-8's inline f64 PE blew VGPR to 256, occupancy 7%).
__global__ __launch_bounds__(256) void k_conv_ln_pe_qkv(const float* __restrict__ xn,
    const float* __restrict__ cw, const float* __restrict__ cb,
    const float* __restrict__ g0, const float* __restrict__ bt0,
    const float* __restrict__ wqkv, const float* __restrict__ bqkv,
    const float* __restrict__ pe,
    float* __restrict__ x0,
    float* __restrict__ Q, float* __restrict__ K, float* __restrict__ V) {
  __shared__ float w[480], bias[16], gg[16], gb[16];
  __shared__ float wq[768], bq[48];
  for (int i = threadIdx.x; i < 480; i += 256) w[i] = cw[i];
  for (int i = threadIdx.x; i < 768; i += 256) wq[i] = wqkv[i];
  if (threadIdx.x < 16) {
    bias[threadIdx.x] = cb[threadIdx.x];
    gg[threadIdx.x] = g0[threadIdx.x];
    gb[threadIdx.x] = bt0[threadIdx.x];
  }
  if (threadIdx.x < 48) bq[threadIdx.x] = bqkv[threadIdx.x];
  __syncthreads();
  int idx = blockIdx.x * 256 + threadIdx.x;
  int b = idx / 1280, t = idx % 1280;
  const float* xb = xn + (size_t)b * 10 * 1280;
  float in[10][3];
  #pragma unroll
  for (int i = 0; i < 10; i++)
    #pragma unroll
    for (int k = 0; k < 3; k++) {
      int tt = t - 1 + k;
      in[i][k] = (tt >= 0 && tt < 1280) ? xb[i * 1280 + tt] : 0.f;
    }
  float o[16];
  #pragma unroll
  for (int oc = 0; oc < 16; oc++) {
    float a = bias[oc];
    #pragma unroll
    for (int i = 0; i < 10; i++)
      #pragma unroll
      for (int k = 0; k < 3; k++) a += in[i][k] * w[oc * 30 + i * 3 + k];
    o[oc] = fmaxf(a, 0.f);
  }
  float mu = 0.f;
  #pragma unroll
  for (int d = 0; d < 16; d++) mu += o[d];
  mu *= (1.f / 16.f);
  float var = 0.f;
  #pragma unroll
  for (int d = 0; d < 16; d++) { float dd = o[d] - mu; var += dd * dd; }
  var *= (1.f / 16.f);
  float inv = 1.f / sqrtf(var + 1e-5f);
  float xv[16];
  float* outp = x0 + (size_t)idx * 16;
  const float* pep = pe + t * 16;
  #pragma unroll
  for (int d = 0; d < 16; d++) {
    xv[d] = (o[d] - mu) * inv * gg[d] + gb[d] + pep[d];
    outp[d] = xv[d];
  }
  float* qp = Q + (size_t)idx * 16;
  float* kp = K + (size_t)idx * 16;
  float* vp = V + (size_t)idx * 16;
  #pragma unroll
  for (int j = 0; j < 16; j++) {
    float a = bq[j];
    #pragma unroll
    for (int d = 0; d < 16; d++) a += xv[d] * wq[j * 16 + d];
    qp[j] = a;
  }
  #pragma unroll
  for (int j = 0; j < 16; j++) {
    float a = bq[16 + j];
    #pragma unroll
    for (int d = 0; d < 16; d++) a += xv[d] * wq[(16 + j) * 16 + d];
    kp[j] = a;
  }
  #pragma unroll
  for (int j = 0; j < 16; j++) {
    float a = bq[32 + j];
    #pragma unroll
    for (int d = 0; d < 16; d++) a += xv[d] * wq[(32 + j) * 16 + d];
    vp[j] = a;
  }
}

// ---------------- kernel 6: MFMA attention ------------------------------------
#define ATT_SHIFT 12.0f
__global__ __launch_bounds__(256) void k_attn_mfma(const float* __restrict__ Q,
    const float* __restrict__ K, const float* __restrict__ V,
    float* __restrict__ A) {
  __shared__ __align__(16) _Float16 Ks[64 * 40];   // [key][d], d 16..31 zero
  __shared__ __align__(16) _Float16 Vt[16 * 72];   // [d][key]
  __shared__ __align__(16) _Float16 Pld[4][16 * 40]; // per-wave [qrow][key32]
  int tid = threadIdx.x;
  int b  = blockIdx.x / 20;
  int rg = blockIdx.x % 20;
  int wv = tid >> 6;
  int lane = tid & 63;
  int col = lane & 15;
  int quad = lane >> 4;
  size_t base = (size_t)b * 1280;
  int row0 = rg * 64 + wv * 16;

  f16x8 qf;
  #pragma unroll
  for (int j = 0; j < 8; j++) qf[j] = (_Float16)0.f;
  if (quad < 2) {
    const float* qp = Q + (base + row0 + col) * 16 + quad * 8;
    #pragma unroll
    for (int j = 0; j < 8; j++) qf[j] = (_Float16)(0.25f * qp[j]);
  }
  f32x4 oacc = {0.f, 0.f, 0.f, 0.f};
  float lacc = 0.f;

  for (int s = 0; s < 20; s++) {
    __syncthreads();
    {
      int key = tid >> 2, part = tid & 3;
      const float* kp = K + (base + s * 64 + key) * 16 + part * 4;
      f16x4 hk, hz;
      #pragma unroll
      for (int j = 0; j < 4; j++) { hk[j] = (_Float16)kp[j]; hz[j] = (_Float16)0.f; }
      *(f16x4*)&Ks[key * 40 + part * 4] = hk;
      *(f16x4*)&Ks[key * 40 + 16 + part * 4] = hz;
      const float* vp = V + (base + s * 64 + key) * 16 + part * 4;
      #pragma unroll
      for (int j = 0; j < 4; j++) Vt[(part * 4 + j) * 72 + key] = (_Float16)vp[j];
    }
    __syncthreads();
    #pragma unroll
    for (int c = 0; c < 2; c++) {
      #pragma unroll
      for (int t = 0; t < 2; t++) {
        int keyoff = c * 32 + t * 16;
        f16x8 af = *(f16x8*)&Ks[(keyoff + col) * 40 + quad * 8];
        f32x4 sf = {0.f, 0.f, 0.f, 0.f};
        sf = __builtin_amdgcn_mfma_f32_16x16x32_f16(af, qf, sf, 0, 0, 0);
        f16x4 ph;
        float psum = 0.f;
        #pragma unroll
        for (int r = 0; r < 4; r++) {
          float p = __expf(sf[r] - ATT_SHIFT);
          psum += p;
          ph[r] = (_Float16)p;
        }
        lacc += psum;
        *(f16x4*)&Pld[wv][col * 40 + t * 16 + quad * 4] = ph;
      }
      __syncthreads();
      f16x8 pf = *(f16x8*)&Pld[wv][col * 40 + quad * 8];
      f16x8 vf = *(f16x8*)&Vt[col * 72 + c * 32 + quad * 8];
      oacc = __builtin_amdgcn_mfma_f32_16x16x32_f16(pf, vf, oacc, 0, 0, 0);
      __syncthreads();
    }
  }
  lacc += __shfl_xor(lacc, 16, 64);
  lacc += __shfl_xor(lacc, 32, 64);
  #pragma unroll
  for (int r = 0; r < 4; r++) {
    float lr = __shfl(lacc, quad * 4 + r, 64);
    A[(base + row0 + quad * 4 + r) * 16 + col] = oacc[r] / lr;
  }
}

// ---------------- kernel 7: combine + wo + LN1 + FFN + LN2 + pool (fused) -----
__global__ __launch_bounds__(256) void k_combine_pool(
    const float* __restrict__ A, const float* __restrict__ x0,
    const float* __restrict__ wo, const float* __restrict__ bo,
    const float* __restrict__ w1, const float* __restrict__ b1,
    const float* __restrict__ w2, const float* __restrict__ b2,
    const float* __restrict__ g1, const float* __restrict__ bb1,
    const float* __restrict__ g2, const float* __restrict__ bb2,
    const float* __restrict__ wfc, const float* __restrict__ bfc,
    float* __restrict__ out) {
  __shared__ float swo[256], sw1[512], sw2[512];
  __shared__ float sbo[16], sb1[32], sb2[16], sg1[16], sbb1[16], sg2[16], sbb2[16];
  __shared__ float swf[16];
  int tid = threadIdx.x;
  swo[tid] = wo[tid];
  for (int i = tid; i < 512; i += 256) { sw1[i] = w1[i]; sw2[i] = w2[i]; }
  if (tid < 16) {
    sbo[tid] = bo[tid]; sb2[tid] = b2[tid];
    sg1[tid] = g1[tid]; sbb1[tid] = bb1[tid];
    sg2[tid] = g2[tid]; sbb2[tid] = bb2[tid];
    swf[tid] = wfc[tid];
  }
  if (tid < 32) sb1[tid] = b1[tid];
  __syncthreads();

  int idx = blockIdx.x * 256 + tid;          // [0, 81920)
  int bb = blockIdx.x / 5;
  const float* pa = A + (size_t)idx * 16;
  float a[16];
  #pragma unroll
  for (int d = 0; d < 16; d++) a[d] = pa[d];
  float h[16];
  const float* xr = x0 + (size_t)idx * 16;
  #pragma unroll
  for (int d = 0; d < 16; d++) {
    float o = sbo[d];
    #pragma unroll
    for (int e = 0; e < 16; e++) o += a[e] * swo[d * 16 + e];
    h[d] = xr[d] + o;
  }
  float mu = 0.f;
  #pragma unroll
  for (int d = 0; d < 16; d++) mu += h[d];
  mu *= (1.f / 16.f);
  float var = 0.f;
  #pragma unroll
  for (int d = 0; d < 16; d++) { float dd = h[d] - mu; var += dd * dd; }
  var *= (1.f / 16.f);
  float inv = 1.f / sqrtf(var + 1e-5f);
  float x1[16];
  #pragma unroll
  for (int d = 0; d < 16; d++) x1[d] = (h[d] - mu) * inv * sg1[d] + sbb1[d];
  float t1[32];
  #pragma unroll
  for (int j = 0; j < 32; j++) {
    float u = sb1[j];
    #pragma unroll
    for (int d = 0; d < 16; d++) u += x1[d] * sw1[j * 16 + d];
    t1[j] = fmaxf(u, 0.f);
  }
  float h2[16];
  #pragma unroll
  for (int d = 0; d < 16; d++) {
    float u = sb2[d];
    #pragma unroll
    for (int j = 0; j < 32; j++) u += t1[j] * sw2[d * 32 + j];
    h2[d] = x1[d] + u;
  }
  mu = 0.f;
  #pragma unroll
  for (int d = 0; d < 16; d++) mu += h2[d];
  mu *= (1.f / 16.f);
  var = 0.f;
  #pragma unroll
  for (int d = 0; d < 16; d++) { float dd = h2[d] - mu; var += dd * dd; }
  var *= (1.f / 16.f);
  inv = 1.f / sqrtf(var + 1e-5f);
  float pv = 0.f;
  #pragma unroll
  for (int d = 0; d < 16; d++)
    pv += ((h2[d] - mu) * inv * sg2[d] + sbb2[d]) * swf[d];
  double part = waveReduceSum((double)pv);
  __shared__ double red[4];
  int wid = tid >> 6, lane = tid & 63;
  if (lane == 0) red[wid] = part;
  __syncthreads();
  if (tid == 0) {
    double S = red[0] + red[1] + red[2] + red[3];
    float add = (float)(S / 1280.0);
    if (blockIdx.x % 5 == 0) add += bfc[0];
    atomicAdd(&out[bb], add);
  }
}

// ---------------- launch ------------------------------------------------------
extern "C" void kernel_launch(void* const* d_in, const int* in_sizes, int n_in,
                              void* d_out, int out_size, void* d_ws, size_t ws_size,
                              hipStream_t stream) {
  const float* x    = (const float*)d_in[0];
  const float* cw   = (const float*)d_in[1];
  const float* cb   = (const float*)d_in[2];
  const float* g0   = (const float*)d_in[3];
  const float* bt0  = (const float*)d_in[4];
  const float* wqkv = (const float*)d_in[5];
  const float* bqkv = (const float*)d_in[6];
  const float* wo   = (const float*)d_in[7];
  const float* bo   = (const float*)d_in[8];
  const float* w1   = (const float*)d_in[9];
  const float* b1   = (const float*)d_in[10];
  const float* w2   = (const float*)d_in[11];
  const float* b2   = (const float*)d_in[12];
  const float* g1   = (const float*)d_in[13];
  const float* bb1  = (const float*)d_in[14];
  const float* g2   = (const float*)d_in[15];
  const float* bb2  = (const float*)d_in[16];
  const float* wfc  = (const float*)d_in[17];
  const float* bfc  = (const float*)d_in[18];
  float* out = (float*)d_out;

  float* ws = (float*)d_ws;
  float* xs = ws;                       // 640*2000 = 1,280,000 (filtered in-place;
                                        // dead after k_resample_norm -> reused as A)
  float* y1 = xs + 1280000;             // spacer (dead)
  float* xn = y1 + 1306880;             // 640*1280   =   819,200
  float* x0 = xn + 819200;              // 64*1280*16 = 1,310,720
  float* Q  = x0 + 1310720;
  float* Kb = Q  + 1310720;
  float* Vb = Kb + 1310720;
  float* pe = Vb + 1310720;             // 1280*16 = 20,480  (total ~36 MB)
  float* Abuf = ws;                     // attention output (reuses dead xs)

  FiltArg fc; CorArg co; FirArg fa;
  build_filt(fc, co);
  design_fir(fa);

  k_chansel<<<(64 * 2000 + 255) / 256, 256, 0, stream>>>(x, xs);
  k_filtfilt<<<640, 64, 0, stream>>>(xs, fc, co);
  k_pe<<<(1280 * 16 + 255) / 256, 256, 0, stream>>>(pe);
  k_resample_norm<<<640, 256, 0, stream>>>(xs, xn, fa);
  k_conv_ln_pe_qkv<<<320, 256, 0, stream>>>(xn, cw, cb, g0, bt0, wqkv, bqkv,
                                            pe, x0, Q, Kb, Vb);
  k_attn_mfma<<<1280, 256, 0, stream>>>(Q, Kb, Vb, Abuf);
  hipMemsetAsync(out, 0, 64 * sizeof(float), stream);
  k_combine_pool<<<320, 256, 0, stream>>>(Abuf, x0, wo, bo, w1, b1, w2, b2,
                                          g1, bb1, g2, bb2, wfc, bfc, out);
}

// Round 10
// 256.855 us; speedup vs baseline: 1.9055x; 1.0021x over previous
//
#include <hip/hip_runtime.h>
#include <cmath>
#include <complex>
#include <algorithm>

#ifndef M_PI
#define M_PI 3.14159265358979323846
#endif

typedef _Float16 f16x8 __attribute__((ext_vector_type(8)));
typedef _Float16 f16x4 __attribute__((ext_vector_type(4)));
typedef float f32x4 __attribute__((ext_vector_type(4)));

// ---------------- coefficient structs (passed by value as kernel args) ---------
struct FiltArg {
  double b0[3], b1[3], b2[3], a1[3], a2[3];
  double zi0[3], zi1[3];
  double A32[36];              // (state-transition matrix)^32, 6x6 row-major
};
struct CorArg { double CA[32 * 6]; };  // CA[i][j] = output at step i from unit state e_j
struct FirArg { float h[526]; };  // 25 leading zeros + 501-tap kaiser-sinc, *UP

// ---------------- host-side filter design (exact replica of reference) --------
static void design_sos(FiltArg& sa) {
  const int order = 6;
  const double wn = 0.5 / 50.0;
  const double fs = 2.0;
  double warped = 2.0 * fs * std::tan(M_PI * wn / fs);
  std::complex<double> p[6];
  for (int i = 0; i < order; i++) {
    int m = -order + 1 + 2 * i;                      // -5,-3,-1,1,3,5
    p[i] = -std::exp(std::complex<double>(0.0, M_PI * m / (2.0 * order)));
  }
  std::complex<double> prod1(1, 0);
  for (int i = 0; i < 6; i++) prod1 *= -p[i];
  double k = (1.0 / prod1).real();
  for (int i = 0; i < 6; i++) p[i] = warped / p[i];
  const double fs2 = 2.0 * fs;
  std::complex<double> num(1, 0), den(1, 0);
  for (int i = 0; i < 6; i++) { num *= fs2; den *= (fs2 - p[i]); }
  k *= (num / den).real();
  for (int i = 0; i < 6; i++) p[i] = (fs2 + p[i]) / (fs2 - p[i]);
  std::complex<double> pp[3]; int n = 0;
  for (int i = 0; i < 6; i++) if (p[i].imag() > 0) pp[n++] = p[i];
  std::stable_sort(pp, pp + 3,
    [](const std::complex<double>& A, const std::complex<double>& B) {
      return std::fabs(std::abs(A) - 1.0) > std::fabs(std::abs(B) - 1.0);
    });
  double sos[3][6];
  for (int s = 0; s < 3; s++) {
    double g = (s == 0) ? k : 1.0;
    sos[s][0] = g; sos[s][1] = -2.0 * g; sos[s][2] = g;
    sos[s][3] = 1.0; sos[s][4] = -2.0 * pp[s].real(); sos[s][5] = std::norm(pp[s]);
  }
  double scale = 1.0;
  for (int s = 0; s < 3; s++) {
    double b0 = sos[s][0], b1 = sos[s][1], b2 = sos[s][2];
    double a1 = sos[s][4], a2 = sos[s][5];
    double det = 1.0 + a1 + a2;                      // det of [[1+a1,-1],[a2,1]]
    double r0 = b1 - a1 * b0, r1 = b2 - a2 * b0;
    double z0 = (r0 + r1) / det;
    double z1 = ((1.0 + a1) * r1 - a2 * r0) / det;
    sa.b0[s] = b0; sa.b1[s] = b1; sa.b2[s] = b2; sa.a1[s] = a1; sa.a2[s] = a2;
    sa.zi0[s] = scale * z0; sa.zi1[s] = scale * z1;
    scale *= (b0 + b1 + b2) / (1.0 + a1 + a2);
  }
}

static double host_step(const FiltArg& c, double z[6], double v) {
  for (int s = 0; s < 3; s++) {
    double y = c.b0[s] * v + z[2 * s];
    z[2 * s]     = c.b1[s] * v - c.a1[s] * y + z[2 * s + 1];
    z[2 * s + 1] = c.b2[s] * v - c.a2[s] * y;
    v = y;
  }
  return v;
}

static void build_filt(FiltArg& c, CorArg& co) {
  design_sos(c);
  double A[36];
  for (int j = 0; j < 6; j++) {
    double z[6] = {0, 0, 0, 0, 0, 0};
    z[j] = 1.0;
    host_step(c, z, 0.0);
    for (int i = 0; i < 6; i++) A[i * 6 + j] = z[i];
  }
  double M[36], T[36];
  for (int i = 0; i < 36; i++) M[i] = A[i];
  for (int sq = 0; sq < 5; sq++) {
    for (int i = 0; i < 6; i++)
      for (int j = 0; j < 6; j++) {
        double s = 0.0;
        for (int kk = 0; kk < 6; kk++) s += M[i * 6 + kk] * M[kk * 6 + j];
        T[i * 6 + j] = s;
      }
    for (int i = 0; i < 36; i++) M[i] = T[i];
  }
  for (int i = 0; i < 36; i++) c.A32[i] = M[i];
  // CA[i][j]: output at chunk-step i starting from unit state e_j, zero input
  for (int j = 0; j < 6; j++) {
    double z[6] = {0, 0, 0, 0, 0, 0};
    z[j] = 1.0;
    for (int i = 0; i < 32; i++) co.CA[i * 6 + j] = host_step(c, z, 0.0);
  }
}

static double bessel_i0(double x) {
  double s = 1.0, t = 1.0;
  for (int k = 1; k < 64; k++) {
    double u = x / (2.0 * k);
    t *= u * u; s += t;
    if (t < 1e-18 * s) break;
  }
  return s;
}

static void design_fir(FirArg& fa) {
  double h[501];
  const double fc = 1.0 / 25.0;
  double denom = bessel_i0(5.0);
  double sum = 0.0;
  for (int nn = 0; nn < 501; nn++) {
    double m = nn - 250.0;
    double xx = fc * m;
    double snc = (nn == 250) ? 1.0 : std::sin(M_PI * xx) / (M_PI * xx);
    double r = (2.0 * nn) / 500.0 - 1.0;
    double w = bessel_i0(5.0 * std::sqrt(std::max(0.0, 1.0 - r * r))) / denom;
    h[nn] = fc * snc * w; sum += h[nn];
  }
  for (int nn = 0; nn < 25; nn++) fa.h[nn] = 0.0f;          // n_pre_pad = 25
  for (int nn = 0; nn < 501; nn++) fa.h[25 + nn] = (float)(h[nn] / sum * 16.0);
}

// ---------------- device helpers ----------------
__device__ inline double waveReduceSum(double v) {
  #pragma unroll
  for (int off = 32; off > 0; off >>= 1) v += __shfl_down(v, off, 64);
  return v;
}

// ---------------- kernel 1: chansel + demean, PE table, out-zero (merged) -----
// Blocks [0,500): channel select + demean (500*256 = 128000 = 64*2000 exact).
// Blocks [500,580): PE table (80*256 = 20480 = 1280*16 exact). Last block also
// zeros d_out (needed by k_combine_pool's atomic accumulation).
__global__ __launch_bounds__(256) void k_chansel_pe(const float* __restrict__ x,
                                                    float* __restrict__ xs,
                                                    float* __restrict__ pe,
                                                    float* __restrict__ out) {
  int gid = blockIdx.x;
  if (gid < 500) {
    int idx = gid * 256 + threadIdx.x;
    int b = idx / 2000, t = idx % 2000;
    const int ch[10] = {126, 125, 48, 112, 67, 93, 10, 61, 39, 108};
    const float* xb = x + (size_t)b * 128 * 2000;
    float v[10]; float s = 0.f;
    #pragma unroll
    for (int c = 0; c < 10; c++) { v[c] = xb[ch[c] * 2000 + t]; s += v[c]; }
    s *= 0.1f;
    #pragma unroll
    for (int c = 0; c < 10; c++) xs[((size_t)b * 10 + c) * 2000 + t] = v[c] - s;
  } else {
    int i = (gid - 500) * 256 + threadIdx.x;    // [0, 20480)
    int t = i >> 4, d = i & 15, j = d >> 1;
    double div = exp(-((double)(2 * j)) * 0.5756462732485114); // ln(10000)/16
    double a = (double)t * div;
    pe[i] = (float)((d & 1) ? cos(a) : sin(a));
    if (gid == 579 && threadIdx.x < 64) out[threadIdx.x] = 0.f;
  }
}

// ---------------- kernel 2: filtfilt, LDS pass1 + parallel correction ---------
// One block = one wave per row. y_true[i] = y_zero[i] + CA[i].z_start (exact
// linear decomposition). Zero-state outputs go to LDS, NOT registers --
// round-8's yreg[32] (64 VGPRs) exceeded the 88-VGPR budget and spilled to
// scratch in the serial chain. Backward zero-state reuses xr (f32; ~1e-7 err).
#define XR(t) xr[(t) + ((t) >> 5)]
#define YF(t) yf[(t) + ((t) >> 5)]
__global__ __launch_bounds__(64) void k_filtfilt(float* __restrict__ xs,
                                                 FiltArg c, CorArg co) {
  __shared__ float xr[2112];      // extended input seq; later backward y_zero
  __shared__ double yf[2112];     // forward output (zero-state, then corrected)
  __shared__ double Fs[64][7];
  __shared__ double Zs[64][7];
  int r = blockIdx.x;
  int k = threadIdx.x;
  float* x = xs + (size_t)r * 2000;

  float x0f = x[0], xlf = x[1999];
  for (int t = k; t < 2048; t += 64) {
    float v;
    if (t < 21)        v = 2.f * x0f - x[21 - t];
    else if (t < 2021) v = x[t - 21];
    else if (t < 2042) v = 2.f * xlf - x[4019 - t];
    else               v = 0.f;
    XR(t) = v;
  }
  __syncthreads();

  double b0[3], b1[3], b2[3], a1[3], a2[3];
  #pragma unroll
  for (int s = 0; s < 3; s++) {
    b0[s] = c.b0[s]; b1[s] = c.b1[s]; b2[s] = c.b2[s];
    a1[s] = c.a1[s]; a2[s] = c.a2[s];
  }
  auto step = [&](double* z, double v) -> double {
    #pragma unroll
    for (int s = 0; s < 3; s++) {
      double y = b0[s] * v + z[2 * s];
      z[2 * s]     = b1[s] * v - a1[s] * y + z[2 * s + 1];
      z[2 * s + 1] = b2[s] * v - a2[s] * y;
      v = y;
    }
    return v;
  };
  double arow[6] = {0, 0, 0, 0, 0, 0};
  if (k < 6) {
    #pragma unroll
    for (int j = 0; j < 6; j++) arow[j] = c.A32[k * 6 + j];
  }
  int li = (k < 6) ? k : 0;
  auto scan = [&](double seed) {
    double zz = 0.0;
    if (k < 6) zz = ((k & 1) ? c.zi1[k >> 1] : c.zi0[k >> 1]) * seed;
    for (int kk = 0; kk < 64; kk++) {
      if (k < 6) Zs[kk][k] = zz;
      double f = Fs[kk][li];
      double nz = f;
      #pragma unroll
      for (int j = 0; j < 6; j++) nz += arow[j] * __shfl(zz, j, 64);
      zz = nz;
    }
  };

  int t0 = k * 32;
  double z[6];
  double seedF = (double)XR(0);

  // ---- forward: zero-state pass -> LDS ----
  #pragma unroll
  for (int i = 0; i < 6; i++) z[i] = 0.0;
  for (int i = 0; i < 32; i++) YF(t0 + i) = step(z, (double)XR(t0 + i));
  #pragma unroll
  for (int i = 0; i < 6; i++) Fs[k][i] = z[i];
  __syncthreads();
  scan(seedF);
  __syncthreads();
  // ---- forward correction in-place (own region; parallel) ----
  #pragma unroll
  for (int i = 0; i < 6; i++) z[i] = Zs[k][i];
  for (int i = 0; i < 32; i++) {
    double corr = 0.0;
    #pragma unroll
    for (int j = 0; j < 6; j++) corr += co.CA[i * 6 + j] * z[j];
    YF(t0 + i) += corr;
  }
  __syncthreads();

  // ---- backward over reversed yf; zero-state outputs reuse xr (f32) ----
  auto rin = [&](int j) -> double { return (j <= 2041) ? YF(2041 - j) : 0.0; };
  double seedB = YF(2041);
  #pragma unroll
  for (int i = 0; i < 6; i++) z[i] = 0.0;
  for (int i = 0; i < 32; i++) XR(t0 + i) = (float)step(z, rin(t0 + i));
  #pragma unroll
  for (int i = 0; i < 6; i++) Fs[k][i] = z[i];
  __syncthreads();
  scan(seedB);
  __syncthreads();
  #pragma unroll
  for (int i = 0; i < 6; i++) z[i] = Zs[k][i];
  for (int i = 0; i < 32; i++) {
    int j = t0 + i;
    if (j >= 21 && j <= 2020) {
      double corr = 0.0;
      #pragma unroll
      for (int jj = 0; jj < 6; jj++) corr += co.CA[i * 6 + jj] * z[jj];
      x[2020 - j] = (float)((double)XR(t0 + i) + corr);   // reversed + trimmed
    }
  }
}

// ---------------- kernel 3: polyphase resample + tanh + per-row normalize ----
__global__ __launch_bounds__(256) void k_resample_norm(const float* __restrict__ xf,
                                                       float* __restrict__ xn,
                                                       FirArg fa) {
  __shared__ float xl[2000];
  __shared__ float hl[526];
  int r = blockIdx.x;                         // 640 rows
  const float* x = xf + (size_t)r * 2000;
  for (int i = threadIdx.x; i < 2000; i += 256) xl[i] = x[i];
  for (int i = threadIdx.x; i < 526; i += 256) hl[i] = fa.h[i];
  __syncthreads();
  float vals[5];
  #pragma unroll
  for (int kk = 0; kk < 5; kk++) {
    int o = threadIdx.x + kk * 256;           // 1280 outputs per row
    int P = 25 * (o + 11);
    int phase = P & 15;
    float acc = 0.f;
    for (int m = phase; m <= 525; m += 16) {
      int idx = (P - m) >> 4;
      if (idx >= 0 && idx < 2000) acc += hl[m] * xl[idx];
    }
    vals[kk] = tanhf(acc);
  }
  double s = 0.0, ss = 0.0;
  #pragma unroll
  for (int kk = 0; kk < 5; kk++) {
    s += (double)vals[kk]; ss += (double)vals[kk] * (double)vals[kk];
  }
  s = waveReduceSum(s); ss = waveReduceSum(ss);
  __shared__ double red[8];
  int wid = threadIdx.x >> 6, lane = threadIdx.x & 63;
  if (lane == 0) { red[wid] = s; red[4 + wid] = ss; }
  __syncthreads();
  double S = red[0] + red[1] + red[2] + red[3];
  double SS = red[4] + red[5] + red[6] + red[7];
  double mean = S / 1280.0;
  double var = (SS - 1280.0 * mean * mean) / 1279.0;
  double sd = fmax(sqrt(fmax(var, 0.0)), 1e-6);
  float fmean = (float)mean, finv = (float)(1.0 / sd);
  #pragma unroll
  for (int kk = 0; kk < 5; kk++)
    xn[(size_t)r * 1280 + threadIdx.x + kk * 256] = (vals[kk] - fmean) * finv;
}

// ---------------- kernel 4: conv1d + relu + LN + PE(table) + QKV (fused) ------
__global__ __launch_bounds__(256) void k_conv_ln_pe_qkv(const float* __restrict__ xn,
    const float* __restrict__ cw, const float* __restrict__ cb,
    const float* __restrict__ g0, const float* __restrict__ bt0,
    const float* __restrict__ wqkv, const float* __restrict__ bqkv,
    const float* __restrict__ pe,
    float* __restrict__ x0,
    float* __restrict__ Q, float* __restrict__ K, float* __restrict__ V) {
  __shared__ float w[480], bias[16], gg[16], gb[16];
  __shared__ float wq[768], bq[48];
  for (int i = threadIdx.x; i < 480; i += 256) w[i] = cw[i];
  for (int i = threadIdx.x; i < 768; i += 256) wq[i] = wqkv[i];
  if (threadIdx.x < 16) {
    bias[threadIdx.x] = cb[threadIdx.x];
    gg[threadIdx.x] = g0[threadIdx.x];
    gb[threadIdx.x] = bt0[threadIdx.x];
  }
  if (threadIdx.x < 48) bq[threadIdx.x] = bqkv[threadIdx.x];
  __syncthreads();
  int idx = blockIdx.x * 256 + threadIdx.x;
  int b = idx / 1280, t = idx % 1280;
  const float* xb = xn + (size_t)b * 10 * 1280;
  float in[10][3];
  #pragma unroll
  for (int i = 0; i < 10; i++)
    #pragma unroll
    for (int k = 0; k < 3; k++) {
      int tt = t - 1 + k;
      in[i][k] = (tt >= 0 && tt < 1280) ? xb[i * 1280 + tt] : 0.f;
    }
  float o[16];
  #pragma unroll
  for (int oc = 0; oc < 16; oc++) {
    float a = bias[oc];
    #pragma unroll
    for (int i = 0; i < 10; i++)
      #pragma unroll
      for (int k = 0; k < 3; k++) a += in[i][k] * w[oc * 30 + i * 3 + k];
    o[oc] = fmaxf(a, 0.f);
  }
  float mu = 0.f;
  #pragma unroll
  for (int d = 0; d < 16; d++) mu += o[d];
  mu *= (1.f / 16.f);
  float var = 0.f;
  #pragma unroll
  for (int d = 0; d < 16; d++) { float dd = o[d] - mu; var += dd * dd; }
  var *= (1.f / 16.f);
  float inv = 1.f / sqrtf(var + 1e-5f);
  float xv[16];
  float* outp = x0 + (size_t)idx * 16;
  const float* pep = pe + t * 16;
  #pragma unroll
  for (int d = 0; d < 16; d++) {
    xv[d] = (o[d] - mu) * inv * gg[d] + gb[d] + pep[d];
    outp[d] = xv[d];
  }
  float* qp = Q + (size_t)idx * 16;
  float* kp = K + (size_t)idx * 16;
  float* vp = V + (size_t)idx * 16;
  #pragma unroll
  for (int j = 0; j < 16; j++) {
    float a = bq[j];
    #pragma unroll
    for (int d = 0; d < 16; d++) a += xv[d] * wq[j * 16 + d];
    qp[j] = a;
  }
  #pragma unroll
  for (int j = 0; j < 16; j++) {
    float a = bq[16 + j];
    #pragma unroll
    for (int d = 0; d < 16; d++) a += xv[d] * wq[(16 + j) * 16 + d];
    kp[j] = a;
  }
  #pragma unroll
  for (int j = 0; j < 16; j++) {
    float a = bq[32 + j];
    #pragma unroll
    for (int d = 0; d < 16; d++) a += xv[d] * wq[(32 + j) * 16 + d];
    vp[j] = a;
  }
}

// ---------------- kernel 5: MFMA attention ------------------------------------
#define ATT_SHIFT 12.0f
__global__ __launch_bounds__(256) void k_attn_mfma(const float* __restrict__ Q,
    const float* __restrict__ K, const float* __restrict__ V,
    float* __restrict__ A) {
  __shared__ __align__(16) _Float16 Ks[64 * 40];   // [key][d], d 16..31 zero
  __shared__ __align__(16) _Float16 Vt[16 * 72];   // [d][key]
  __shared__ __align__(16) _Float16 Pld[4][16 * 40]; // per-wave [qrow][key32]
  int tid = threadIdx.x;
  int b  = blockIdx.x / 20;
  int rg = blockIdx.x % 20;
  int wv = tid >> 6;
  int lane = tid & 63;
  int col = lane & 15;
  int quad = lane >> 4;
  size_t base = (size_t)b * 1280;
  int row0 = rg * 64 + wv * 16;

  f16x8 qf;
  #pragma unroll
  for (int j = 0; j < 8; j++) qf[j] = (_Float16)0.f;
  if (quad < 2) {
    const float* qp = Q + (base + row0 + col) * 16 + quad * 8;
    #pragma unroll
    for (int j = 0; j < 8; j++) qf[j] = (_Float16)(0.25f * qp[j]);
  }
  f32x4 oacc = {0.f, 0.f, 0.f, 0.f};
  float lacc = 0.f;

  for (int s = 0; s < 20; s++) {
    __syncthreads();
    {
      int key = tid >> 2, part = tid & 3;
      const float* kp = K + (base + s * 64 + key) * 16 + part * 4;
      f16x4 hk, hz;
      #pragma unroll
      for (int j = 0; j < 4; j++) { hk[j] = (_Float16)kp[j]; hz[j] = (_Float16)0.f; }
      *(f16x4*)&Ks[key * 40 + part * 4] = hk;
      *(f16x4*)&Ks[key * 40 + 16 + part * 4] = hz;
      const float* vp = V + (base + s * 64 + key) * 16 + part * 4;
      #pragma unroll
      for (int j = 0; j < 4; j++) Vt[(part * 4 + j) * 72 + key] = (_Float16)vp[j];
    }
    __syncthreads();
    #pragma unroll
    for (int c = 0; c < 2; c++) {
      #pragma unroll
      for (int t = 0; t < 2; t++) {
        int keyoff = c * 32 + t * 16;
        f16x8 af = *(f16x8*)&Ks[(keyoff + col) * 40 + quad * 8];
        f32x4 sf = {0.f, 0.f, 0.f, 0.f};
        sf = __builtin_amdgcn_mfma_f32_16x16x32_f16(af, qf, sf, 0, 0, 0);
        f16x4 ph;
        float psum = 0.f;
        #pragma unroll
        for (int r = 0; r < 4; r++) {
          float p = __expf(sf[r] - ATT_SHIFT);
          psum += p;
          ph[r] = (_Float16)p;
        }
        lacc += psum;
        *(f16x4*)&Pld[wv][col * 40 + t * 16 + quad * 4] = ph;
      }
      __syncthreads();
      f16x8 pf = *(f16x8*)&Pld[wv][col * 40 + quad * 8];
      f16x8 vf = *(f16x8*)&Vt[col * 72 + c * 32 + quad * 8];
      oacc = __builtin_amdgcn_mfma_f32_16x16x32_f16(pf, vf, oacc, 0, 0, 0);
      __syncthreads();
    }
  }
  lacc += __shfl_xor(lacc, 16, 64);
  lacc += __shfl_xor(lacc, 32, 64);
  #pragma unroll
  for (int r = 0; r < 4; r++) {
    float lr = __shfl(lacc, quad * 4 + r, 64);
    A[(base + row0 + quad * 4 + r) * 16 + col] = oacc[r] / lr;
  }
}

// ---------------- kernel 6: combine + wo + LN1 + FFN + LN2 + pool (fused) -----
__global__ __launch_bounds__(256) void k_combine_pool(
    const float* __restrict__ A, const float* __restrict__ x0,
    const float* __restrict__ wo, const float* __restrict__ bo,
    const float* __restrict__ w1, const float* __restrict__ b1,
    const float* __restrict__ w2, const float* __restrict__ b2,
    const float* __restrict__ g1, const float* __restrict__ bb1,
    const float* __restrict__ g2, const float* __restrict__ bb2,
    const float* __restrict__ wfc, const float* __restrict__ bfc,
    float* __restrict__ out) {
  __shared__ float swo[256], sw1[512], sw2[512];
  __shared__ float sbo[16], sb1[32], sb2[16], sg1[16], sbb1[16], sg2[16], sbb2[16];
  __shared__ float swf[16];
  int tid = threadIdx.x;
  swo[tid] = wo[tid];
  for (int i = tid; i < 512; i += 256) { sw1[i] = w1[i]; sw2[i] = w2[i]; }
  if (tid < 16) {
    sbo[tid] = bo[tid]; sb2[tid] = b2[tid];
    sg1[tid] = g1[tid]; sbb1[tid] = bb1[tid];
    sg2[tid] = g2[tid]; sbb2[tid] = bb2[tid];
    swf[tid] = wfc[tid];
  }
  if (tid < 32) sb1[tid] = b1[tid];
  __syncthreads();

  int idx = blockIdx.x * 256 + tid;          // [0, 81920)
  int bb = blockIdx.x / 5;
  const float* pa = A + (size_t)idx * 16;
  float a[16];
  #pragma unroll
  for (int d = 0; d < 16; d++) a[d] = pa[d];
  float h[16];
  const float* xr = x0 + (size_t)idx * 16;
  #pragma unroll
  for (int d = 0; d < 16; d++) {
    float o = sbo[d];
    #pragma unroll
    for (int e = 0; e < 16; e++) o += a[e] * swo[d * 16 + e];
    h[d] = xr[d] + o;
  }
  float mu = 0.f;
  #pragma unroll
  for (int d = 0; d < 16; d++) mu += h[d];
  mu *= (1.f / 16.f);
  float var = 0.f;
  #pragma unroll
  for (int d = 0; d < 16; d++) { float dd = h[d] - mu; var += dd * dd; }
  var *= (1.f / 16.f);
  float inv = 1.f / sqrtf(var + 1e-5f);
  float x1[16];
  #pragma unroll
  for (int d = 0; d < 16; d++) x1[d] = (h[d] - mu) * inv * sg1[d] + sbb1[d];
  float t1[32];
  #pragma unroll
  for (int j = 0; j < 32; j++) {
    float u = sb1[j];
    #pragma unroll
    for (int d = 0; d < 16; d++) u += x1[d] * sw1[j * 16 + d];
    t1[j] = fmaxf(u, 0.f);
  }
  float h2[16];
  #pragma unroll
  for (int d = 0; d < 16; d++) {
    float u = sb2[d];
    #pragma unroll
    for (int j = 0; j < 32; j++) u += t1[j] * sw2[d * 32 + j];
    h2[d] = x1[d] + u;
  }
  mu = 0.f;
  #pragma unroll
  for (int d = 0; d < 16; d++) mu += h2[d];
  mu *= (1.f / 16.f);
  var = 0.f;
  #pragma unroll
  for (int d = 0; d < 16; d++) { float dd = h2[d] - mu; var += dd * dd; }
  var *= (1.f / 16.f);
  inv = 1.f / sqrtf(var + 1e-5f);
  float pv = 0.f;
  #pragma unroll
  for (int d = 0; d < 16; d++)
    pv += ((h2[d] - mu) * inv * sg2[d] + sbb2[d]) * swf[d];
  double part = waveReduceSum((double)pv);
  __shared__ double red[4];
  int wid = tid >> 6, lane = tid & 63;
  if (lane == 0) red[wid] = part;
  __syncthreads();
  if (tid == 0) {
    double S = red[0] + red[1] + red[2] + red[3];
    float add = (float)(S / 1280.0);
    if (blockIdx.x % 5 == 0) add += bfc[0];
    atomicAdd(&out[bb], add);
  }
}

// ---------------- launch ------------------------------------------------------
extern "C" void kernel_launch(void* const* d_in, const int* in_sizes, int n_in,
                              void* d_out, int out_size, void* d_ws, size_t ws_size,
                              hipStream_t stream) {
  const float* x    = (const float*)d_in[0];
  const float* cw   = (const float*)d_in[1];
  const float* cb   = (const float*)d_in[2];
  const float* g0   = (const float*)d_in[3];
  const float* bt0  = (const float*)d_in[4];
  const float* wqkv = (const float*)d_in[5];
  const float* bqkv = (const float*)d_in[6];
  const float* wo   = (const float*)d_in[7];
  const float* bo   = (const float*)d_in[8];
  const float* w1   = (const float*)d_in[9];
  const float* b1   = (const float*)d_in[10];
  const float* w2   = (const float*)d_in[11];
  const float* b2   = (const float*)d_in[12];
  const float* g1   = (const float*)d_in[13];
  const float* bb1  = (const float*)d_in[14];
  const float* g2   = (const float*)d_in[15];
  const float* bb2  = (const float*)d_in[16];
  const float* wfc  = (const float*)d_in[17];
  const float* bfc  = (const float*)d_in[18];
  float* out = (float*)d_out;

  float* ws = (float*)d_ws;
  float* xs = ws;                       // 640*2000 = 1,280,000 (filtered in-place;
                                        // dead after k_resample_norm -> reused as A)
  float* y1 = xs + 1280000;             // spacer (dead)
  float* xn = y1 + 1306880;             // 640*1280   =   819,200
  float* x0 = xn + 819200;              // 64*1280*16 = 1,310,720
  float* Q  = x0 + 1310720;
  float* Kb = Q  + 1310720;
  float* Vb = Kb + 1310720;
  float* pe = Vb + 1310720;             // 1280*16 = 20,480  (total ~36 MB)
  float* Abuf = ws;                     // attention output (reuses dead xs)

  FiltArg fc; CorArg co; FirArg fa;
  build_filt(fc, co);
  design_fir(fa);

  k_chansel_pe<<<580, 256, 0, stream>>>(x, xs, pe, out);
  k_filtfilt<<<640, 64, 0, stream>>>(xs, fc, co);
  k_resample_norm<<<640, 256, 0, stream>>>(xs, xn, fa);
  k_conv_ln_pe_qkv<<<320, 256, 0, stream>>>(xn, cw, cb, g0, bt0, wqkv, bqkv,
                                            pe, x0, Q, Kb, Vb);
  k_attn_mfma<<<1280, 256, 0, stream>>>(Q, Kb, Vb, Abuf);
  k_combine_pool<<<320, 256, 0, stream>>>(Abuf, x0, wo, bo, w1, b1, w2, b2,
                                          g1, bb1, g2, bb2, wfc, bfc, out);
}

// Round 11
// 250.745 us; speedup vs baseline: 1.9520x; 1.0244x over previous
//
#include <hip/hip_runtime.h>
#include <cmath>
#include <complex>
#include <algorithm>

#ifndef M_PI
#define M_PI 3.14159265358979323846
#endif

typedef _Float16 f16x8 __attribute__((ext_vector_type(8)));
typedef _Float16 f16x4 __attribute__((ext_vector_type(4)));
typedef float f32x4 __attribute__((ext_vector_type(4)));

// ---------------- coefficient structs (passed by value as kernel args) ---------
struct FiltArg {
  double b0[3], b1[3], b2[3], a1[3], a2[3];
  double zi0[3], zi1[3];
  double A32[36];              // (state-transition matrix)^32, 6x6 row-major
};
struct CorArg { double CA[32 * 6]; };  // CA[i][j] = output at step i from unit state e_j
struct FirArg { float h[526]; };  // 25 leading zeros + 501-tap kaiser-sinc, *UP

// ---------------- host-side filter design (exact replica of reference) --------
static void design_sos(FiltArg& sa) {
  const int order = 6;
  const double wn = 0.5 / 50.0;
  const double fs = 2.0;
  double warped = 2.0 * fs * std::tan(M_PI * wn / fs);
  std::complex<double> p[6];
  for (int i = 0; i < order; i++) {
    int m = -order + 1 + 2 * i;                      // -5,-3,-1,1,3,5
    p[i] = -std::exp(std::complex<double>(0.0, M_PI * m / (2.0 * order)));
  }
  std::complex<double> prod1(1, 0);
  for (int i = 0; i < 6; i++) prod1 *= -p[i];
  double k = (1.0 / prod1).real();
  for (int i = 0; i < 6; i++) p[i] = warped / p[i];
  const double fs2 = 2.0 * fs;
  std::complex<double> num(1, 0), den(1, 0);
  for (int i = 0; i < 6; i++) { num *= fs2; den *= (fs2 - p[i]); }
  k *= (num / den).real();
  for (int i = 0; i < 6; i++) p[i] = (fs2 + p[i]) / (fs2 - p[i]);
  std::complex<double> pp[3]; int n = 0;
  for (int i = 0; i < 6; i++) if (p[i].imag() > 0) pp[n++] = p[i];
  std::stable_sort(pp, pp + 3,
    [](const std::complex<double>& A, const std::complex<double>& B) {
      return std::fabs(std::abs(A) - 1.0) > std::fabs(std::abs(B) - 1.0);
    });
  double sos[3][6];
  for (int s = 0; s < 3; s++) {
    double g = (s == 0) ? k : 1.0;
    sos[s][0] = g; sos[s][1] = -2.0 * g; sos[s][2] = g;
    sos[s][3] = 1.0; sos[s][4] = -2.0 * pp[s].real(); sos[s][5] = std::norm(pp[s]);
  }
  double scale = 1.0;
  for (int s = 0; s < 3; s++) {
    double b0 = sos[s][0], b1 = sos[s][1], b2 = sos[s][2];
    double a1 = sos[s][4], a2 = sos[s][5];
    double det = 1.0 + a1 + a2;                      // det of [[1+a1,-1],[a2,1]]
    double r0 = b1 - a1 * b0, r1 = b2 - a2 * b0;
    double z0 = (r0 + r1) / det;
    double z1 = ((1.0 + a1) * r1 - a2 * r0) / det;
    sa.b0[s] = b0; sa.b1[s] = b1; sa.b2[s] = b2; sa.a1[s] = a1; sa.a2[s] = a2;
    sa.zi0[s] = scale * z0; sa.zi1[s] = scale * z1;
    scale *= (b0 + b1 + b2) / (1.0 + a1 + a2);
  }
}

static double host_step(const FiltArg& c, double z[6], double v) {
  for (int s = 0; s < 3; s++) {
    double y = c.b0[s] * v + z[2 * s];
    z[2 * s]     = c.b1[s] * v - c.a1[s] * y + z[2 * s + 1];
    z[2 * s + 1] = c.b2[s] * v - c.a2[s] * y;
    v = y;
  }
  return v;
}

static void build_filt(FiltArg& c, CorArg& co) {
  design_sos(c);
  double A[36];
  for (int j = 0; j < 6; j++) {
    double z[6] = {0, 0, 0, 0, 0, 0};
    z[j] = 1.0;
    host_step(c, z, 0.0);
    for (int i = 0; i < 6; i++) A[i * 6 + j] = z[i];
  }
  double M[36], T[36];
  for (int i = 0; i < 36; i++) M[i] = A[i];
  for (int sq = 0; sq < 5; sq++) {
    for (int i = 0; i < 6; i++)
      for (int j = 0; j < 6; j++) {
        double s = 0.0;
        for (int kk = 0; kk < 6; kk++) s += M[i * 6 + kk] * M[kk * 6 + j];
        T[i * 6 + j] = s;
      }
    for (int i = 0; i < 36; i++) M[i] = T[i];
  }
  for (int i = 0; i < 36; i++) c.A32[i] = M[i];
  // CA[i][j]: output at chunk-step i starting from unit state e_j, zero input
  for (int j = 0; j < 6; j++) {
    double z[6] = {0, 0, 0, 0, 0, 0};
    z[j] = 1.0;
    for (int i = 0; i < 32; i++) co.CA[i * 6 + j] = host_step(c, z, 0.0);
  }
}

static double bessel_i0(double x) {
  double s = 1.0, t = 1.0;
  for (int k = 1; k < 64; k++) {
    double u = x / (2.0 * k);
    t *= u * u; s += t;
    if (t < 1e-18 * s) break;
  }
  return s;
}

static void design_fir(FirArg& fa) {
  double h[501];
  const double fc = 1.0 / 25.0;
  double denom = bessel_i0(5.0);
  double sum = 0.0;
  for (int nn = 0; nn < 501; nn++) {
    double m = nn - 250.0;
    double xx = fc * m;
    double snc = (nn == 250) ? 1.0 : std::sin(M_PI * xx) / (M_PI * xx);
    double r = (2.0 * nn) / 500.0 - 1.0;
    double w = bessel_i0(5.0 * std::sqrt(std::max(0.0, 1.0 - r * r))) / denom;
    h[nn] = fc * snc * w; sum += h[nn];
  }
  for (int nn = 0; nn < 25; nn++) fa.h[nn] = 0.0f;          // n_pre_pad = 25
  for (int nn = 0; nn < 501; nn++) fa.h[25 + nn] = (float)(h[nn] / sum * 16.0);
}

// ---------------- device helpers ----------------
__device__ inline double waveReduceSum(double v) {
  #pragma unroll
  for (int off = 32; off > 0; off >>= 1) v += __shfl_down(v, off, 64);
  return v;
}

// ---------------- kernel 1: chansel + demean, PE table, out-zero (merged) -----
__global__ __launch_bounds__(256) void k_chansel_pe(const float* __restrict__ x,
                                                    float* __restrict__ xs,
                                                    float* __restrict__ pe,
                                                    float* __restrict__ out) {
  int gid = blockIdx.x;
  if (gid < 500) {
    int idx = gid * 256 + threadIdx.x;
    int b = idx / 2000, t = idx % 2000;
    const int ch[10] = {126, 125, 48, 112, 67, 93, 10, 61, 39, 108};
    const float* xb = x + (size_t)b * 128 * 2000;
    float v[10]; float s = 0.f;
    #pragma unroll
    for (int c = 0; c < 10; c++) { v[c] = xb[ch[c] * 2000 + t]; s += v[c]; }
    s *= 0.1f;
    #pragma unroll
    for (int c = 0; c < 10; c++) xs[((size_t)b * 10 + c) * 2000 + t] = v[c] - s;
  } else {
    int i = (gid - 500) * 256 + threadIdx.x;    // [0, 20480)
    int t = i >> 4, d = i & 15, j = d >> 1;
    double div = exp(-((double)(2 * j)) * 0.5756462732485114); // ln(10000)/16
    double a = (double)t * div;
    pe[i] = (float)((d & 1) ? cos(a) : sin(a));
    if (gid == 579 && threadIdx.x < 64) out[threadIdx.x] = 0.f;
  }
}

// ---------------- kernel 2: filtfilt, register pass1 + parallel correction ----
// (round-9 measured-best version: y_zero kept in registers; LDS-resident
// variant measured 71.6us vs this 43.5us -- LDS latency in the serial chain
// at 0.6 waves/SIMD is unhidden. Scan shfl chain is the next target.)
#define XR(t) xr[(t) + ((t) >> 5)]
#define YF(t) yf[(t) + ((t) >> 5)]
__global__ __launch_bounds__(64) void k_filtfilt(float* __restrict__ xs,
                                                 FiltArg c, CorArg co) {
  __shared__ float xr[2112];      // extended input seq (padded)
  __shared__ double yf[2112];     // corrected forward output (padded)
  __shared__ double Fs[64][7];
  __shared__ double Zs[64][7];
  int r = blockIdx.x;
  int k = threadIdx.x;
  float* x = xs + (size_t)r * 2000;

  float x0f = x[0], xlf = x[1999];
  for (int t = k; t < 2048; t += 64) {
    float v;
    if (t < 21)        v = 2.f * x0f - x[21 - t];
    else if (t < 2021) v = x[t - 21];
    else if (t < 2042) v = 2.f * xlf - x[4019 - t];
    else               v = 0.f;
    XR(t) = v;
  }
  __syncthreads();

  double b0[3], b1[3], b2[3], a1[3], a2[3];
  #pragma unroll
  for (int s = 0; s < 3; s++) {
    b0[s] = c.b0[s]; b1[s] = c.b1[s]; b2[s] = c.b2[s];
    a1[s] = c.a1[s]; a2[s] = c.a2[s];
  }
  auto step = [&](double* z, double v) -> double {
    #pragma unroll
    for (int s = 0; s < 3; s++) {
      double y = b0[s] * v + z[2 * s];
      z[2 * s]     = b1[s] * v - a1[s] * y + z[2 * s + 1];
      z[2 * s + 1] = b2[s] * v - a2[s] * y;
      v = y;
    }
    return v;
  };
  double arow[6] = {0, 0, 0, 0, 0, 0};
  if (k < 6) {
    #pragma unroll
    for (int j = 0; j < 6; j++) arow[j] = c.A32[k * 6 + j];
  }
  int li = (k < 6) ? k : 0;
  auto scan = [&](double seed) {
    double zz = 0.0;
    if (k < 6) zz = ((k & 1) ? c.zi1[k >> 1] : c.zi0[k >> 1]) * seed;
    for (int kk = 0; kk < 64; kk++) {
      if (k < 6) Zs[kk][k] = zz;
      double f = Fs[kk][li];
      double nz = f;
      #pragma unroll
      for (int j = 0; j < 6; j++) nz += arow[j] * __shfl(zz, j, 64);
      zz = nz;
    }
  };

  int t0 = k * 32;
  double z[6], yreg[32];

  #pragma unroll
  for (int i = 0; i < 6; i++) z[i] = 0.0;
  for (int i = 0; i < 32; i++) yreg[i] = step(z, (double)XR(t0 + i));
  #pragma unroll
  for (int i = 0; i < 6; i++) Fs[k][i] = z[i];
  __syncthreads();
  scan((double)XR(0));
  __syncthreads();
  #pragma unroll
  for (int i = 0; i < 6; i++) z[i] = Zs[k][i];
  for (int i = 0; i < 32; i++) {
    double corr = 0.0;
    #pragma unroll
    for (int j = 0; j < 6; j++) corr += co.CA[i * 6 + j] * z[j];
    YF(t0 + i) = yreg[i] + corr;
  }
  __syncthreads();

  auto rin = [&](int j) -> double { return (j <= 2041) ? YF(2041 - j) : 0.0; };
  #pragma unroll
  for (int i = 0; i < 6; i++) z[i] = 0.0;
  for (int i = 0; i < 32; i++) yreg[i] = step(z, rin(t0 + i));
  #pragma unroll
  for (int i = 0; i < 6; i++) Fs[k][i] = z[i];
  __syncthreads();
  scan(YF(2041));
  __syncthreads();
  #pragma unroll
  for (int i = 0; i < 6; i++) z[i] = Zs[k][i];
  for (int i = 0; i < 32; i++) {
    int j = t0 + i;
    if (j >= 21 && j <= 2020) {
      double corr = 0.0;
      #pragma unroll
      for (int jj = 0; jj < 6; jj++) corr += co.CA[i * 6 + jj] * z[jj];
      x[2020 - j] = (float)(yreg[i] + corr);   // reversed + trimmed
    }
  }
}

// ---------------- kernel 3: polyphase resample + tanh + per-row normalize ----
__global__ __launch_bounds__(256) void k_resample_norm(const float* __restrict__ xf,
                                                       float* __restrict__ xn,
                                                       FirArg fa) {
  __shared__ float xl[2000];
  __shared__ float hl[526];
  int r = blockIdx.x;                         // 640 rows
  const float* x = xf + (size_t)r * 2000;
  for (int i = threadIdx.x; i < 2000; i += 256) xl[i] = x[i];
  for (int i = threadIdx.x; i < 526; i += 256) hl[i] = fa.h[i];
  __syncthreads();
  float vals[5];
  #pragma unroll
  for (int kk = 0; kk < 5; kk++) {
    int o = threadIdx.x + kk * 256;           // 1280 outputs per row
    int P = 25 * (o + 11);
    int phase = P & 15;
    float acc = 0.f;
    for (int m = phase; m <= 525; m += 16) {
      int idx = (P - m) >> 4;
      if (idx >= 0 && idx < 2000) acc += hl[m] * xl[idx];
    }
    vals[kk] = tanhf(acc);
  }
  double s = 0.0, ss = 0.0;
  #pragma unroll
  for (int kk = 0; kk < 5; kk++) {
    s += (double)vals[kk]; ss += (double)vals[kk] * (double)vals[kk];
  }
  s = waveReduceSum(s); ss = waveReduceSum(ss);
  __shared__ double red[8];
  int wid = threadIdx.x >> 6, lane = threadIdx.x & 63;
  if (lane == 0) { red[wid] = s; red[4 + wid] = ss; }
  __syncthreads();
  double S = red[0] + red[1] + red[2] + red[3];
  double SS = red[4] + red[5] + red[6] + red[7];
  double mean = S / 1280.0;
  double var = (SS - 1280.0 * mean * mean) / 1279.0;
  double sd = fmax(sqrt(fmax(var, 0.0)), 1e-6);
  float fmean = (float)mean, finv = (float)(1.0 / sd);
  #pragma unroll
  for (int kk = 0; kk < 5; kk++)
    xn[(size_t)r * 1280 + threadIdx.x + kk * 256] = (vals[kk] - fmean) * finv;
}

// ---------------- kernel 4: conv1d + relu + LN + PE(table) + QKV (fused) ------
__global__ __launch_bounds__(256) void k_conv_ln_pe_qkv(const float* __restrict__ xn,
    const float* __restrict__ cw, const float* __restrict__ cb,
    const float* __restrict__ g0, const float* __restrict__ bt0,
    const float* __restrict__ wqkv, const float* __restrict__ bqkv,
    const float* __restrict__ pe,
    float* __restrict__ x0,
    float* __restrict__ Q, float* __restrict__ K, float* __restrict__ V) {
  __shared__ float w[480], bias[16], gg[16], gb[16];
  __shared__ float wq[768], bq[48];
  for (int i = threadIdx.x; i < 480; i += 256) w[i] = cw[i];
  for (int i = threadIdx.x; i < 768; i += 256) wq[i] = wqkv[i];
  if (threadIdx.x < 16) {
    bias[threadIdx.x] = cb[threadIdx.x];
    gg[threadIdx.x] = g0[threadIdx.x];
    gb[threadIdx.x] = bt0[threadIdx.x];
  }
  if (threadIdx.x < 48) bq[threadIdx.x] = bqkv[threadIdx.x];
  __syncthreads();
  int idx = blockIdx.x * 256 + threadIdx.x;
  int b = idx / 1280, t = idx % 1280;
  const float* xb = xn + (size_t)b * 10 * 1280;
  float in[10][3];
  #pragma unroll
  for (int i = 0; i < 10; i++)
    #pragma unroll
    for (int k = 0; k < 3; k++) {
      int tt = t - 1 + k;
      in[i][k] = (tt >= 0 && tt < 1280) ? xb[i * 1280 + tt] : 0.f;
    }
  float o[16];
  #pragma unroll
  for (int oc = 0; oc < 16; oc++) {
    float a = bias[oc];
    #pragma unroll
    for (int i = 0; i < 10; i++)
      #pragma unroll
      for (int k = 0; k < 3; k++) a += in[i][k] * w[oc * 30 + i * 3 + k];
    o[oc] = fmaxf(a, 0.f);
  }
  float mu = 0.f;
  #pragma unroll
  for (int d = 0; d < 16; d++) mu += o[d];
  mu *= (1.f / 16.f);
  float var = 0.f;
  #pragma unroll
  for (int d = 0; d < 16; d++) { float dd = o[d] - mu; var += dd * dd; }
  var *= (1.f / 16.f);
  float inv = 1.f / sqrtf(var + 1e-5f);
  float xv[16];
  float* outp = x0 + (size_t)idx * 16;
  const float* pep = pe + t * 16;
  #pragma unroll
  for (int d = 0; d < 16; d++) {
    xv[d] = (o[d] - mu) * inv * gg[d] + gb[d] + pep[d];
    outp[d] = xv[d];
  }
  float* qp = Q + (size_t)idx * 16;
  float* kp = K + (size_t)idx * 16;
  float* vp = V + (size_t)idx * 16;
  #pragma unroll
  for (int j = 0; j < 16; j++) {
    float a = bq[j];
    #pragma unroll
    for (int d = 0; d < 16; d++) a += xv[d] * wq[j * 16 + d];
    qp[j] = a;
  }
  #pragma unroll
  for (int j = 0; j < 16; j++) {
    float a = bq[16 + j];
    #pragma unroll
    for (int d = 0; d < 16; d++) a += xv[d] * wq[(16 + j) * 16 + d];
    kp[j] = a;
  }
  #pragma unroll
  for (int j = 0; j < 16; j++) {
    float a = bq[32 + j];
    #pragma unroll
    for (int d = 0; d < 16; d++) a += xv[d] * wq[(32 + j) * 16 + d];
    vp[j] = a;
  }
}

// ---------------- kernel 5: MFMA attention ------------------------------------
#define ATT_SHIFT 12.0f
__global__ __launch_bounds__(256) void k_attn_mfma(const float* __restrict__ Q,
    const float* __restrict__ K, const float* __restrict__ V,
    float* __restrict__ A) {
  __shared__ __align__(16) _Float16 Ks[64 * 40];   // [key][d], d 16..31 zero
  __shared__ __align__(16) _Float16 Vt[16 * 72];   // [d][key]
  __shared__ __align__(16) _Float16 Pld[4][16 * 40]; // per-wave [qrow][key32]
  int tid = threadIdx.x;
  int b  = blockIdx.x / 20;
  int rg = blockIdx.x % 20;
  int wv = tid >> 6;
  int lane = tid & 63;
  int col = lane & 15;
  int quad = lane >> 4;
  size_t base = (size_t)b * 1280;
  int row0 = rg * 64 + wv * 16;

  f16x8 qf;
  #pragma unroll
  for (int j = 0; j < 8; j++) qf[j] = (_Float16)0.f;
  if (quad < 2) {
    const float* qp = Q + (base + row0 + col) * 16 + quad * 8;
    #pragma unroll
    for (int j = 0; j < 8; j++) qf[j] = (_Float16)(0.25f * qp[j]);
  }
  f32x4 oacc = {0.f, 0.f, 0.f, 0.f};
  float lacc = 0.f;

  for (int s = 0; s < 20; s++) {
    __syncthreads();
    {
      int key = tid >> 2, part = tid & 3;
      const float* kp = K + (base + s * 64 + key) * 16 + part * 4;
      f16x4 hk, hz;
      #pragma unroll
      for (int j = 0; j < 4; j++) { hk[j] = (_Float16)kp[j]; hz[j] = (_Float16)0.f; }
      *(f16x4*)&Ks[key * 40 + part * 4] = hk;
      *(f16x4*)&Ks[key * 40 + 16 + part * 4] = hz;
      const float* vp = V + (base + s * 64 + key) * 16 + part * 4;
      #pragma unroll
      for (int j = 0; j < 4; j++) Vt[(part * 4 + j) * 72 + key] = (_Float16)vp[j];
    }
    __syncthreads();
    #pragma unroll
    for (int c = 0; c < 2; c++) {
      #pragma unroll
      for (int t = 0; t < 2; t++) {
        int keyoff = c * 32 + t * 16;
        f16x8 af = *(f16x8*)&Ks[(keyoff + col) * 40 + quad * 8];
        f32x4 sf = {0.f, 0.f, 0.f, 0.f};
        sf = __builtin_amdgcn_mfma_f32_16x16x32_f16(af, qf, sf, 0, 0, 0);
        f16x4 ph;
        float psum = 0.f;
        #pragma unroll
        for (int r = 0; r < 4; r++) {
          float p = __expf(sf[r] - ATT_SHIFT);
          psum += p;
          ph[r] = (_Float16)p;
        }
        lacc += psum;
        *(f16x4*)&Pld[wv][col * 40 + t * 16 + quad * 4] = ph;
      }
      __syncthreads();
      f16x8 pf = *(f16x8*)&Pld[wv][col * 40 + quad * 8];
      f16x8 vf = *(f16x8*)&Vt[col * 72 + c * 32 + quad * 8];
      oacc = __builtin_amdgcn_mfma_f32_16x16x32_f16(pf, vf, oacc, 0, 0, 0);
      __syncthreads();
    }
  }
  lacc += __shfl_xor(lacc, 16, 64);
  lacc += __shfl_xor(lacc, 32, 64);
  #pragma unroll
  for (int r = 0; r < 4; r++) {
    float lr = __shfl(lacc, quad * 4 + r, 64);
    A[(base + row0 + quad * 4 + r) * 16 + col] = oacc[r] / lr;
  }
}

// ---------------- kernel 6: combine + wo + LN1 + FFN + LN2 + pool (fused) -----
__global__ __launch_bounds__(256) void k_combine_pool(
    const float* __restrict__ A, const float* __restrict__ x0,
    const float* __restrict__ wo, const float* __restrict__ bo,
    const float* __restrict__ w1, const float* __restrict__ b1,
    const float* __restrict__ w2, const float* __restrict__ b2,
    const float* __restrict__ g1, const float* __restrict__ bb1,
    const float* __restrict__ g2, const float* __restrict__ bb2,
    const float* __restrict__ wfc, const float* __restrict__ bfc,
    float* __restrict__ out) {
  __shared__ float swo[256], sw1[512], sw2[512];
  __shared__ float sbo[16], sb1[32], sb2[16], sg1[16], sbb1[16], sg2[16], sbb2[16];
  __shared__ float swf[16];
  int tid = threadIdx.x;
  swo[tid] = wo[tid];
  for (int i = tid; i < 512; i += 256) { sw1[i] = w1[i]; sw2[i] = w2[i]; }
  if (tid < 16) {
    sbo[tid] = bo[tid]; sb2[tid] = b2[tid];
    sg1[tid] = g1[tid]; sbb1[tid] = bb1[tid];
    sg2[tid] = g2[tid]; sbb2[tid] = bb2[tid];
    swf[tid] = wfc[tid];
  }
  if (tid < 32) sb1[tid] = b1[tid];
  __syncthreads();

  int idx = blockIdx.x * 256 + tid;          // [0, 81920)
  int bb = blockIdx.x / 5;
  const float* pa = A + (size_t)idx * 16;
  float a[16];
  #pragma unroll
  for (int d = 0; d < 16; d++) a[d] = pa[d];
  float h[16];
  const float* xr = x0 + (size_t)idx * 16;
  #pragma unroll
  for (int d = 0; d < 16; d++) {
    float o = sbo[d];
    #pragma unroll
    for (int e = 0; e < 16; e++) o += a[e] * swo[d * 16 + e];
    h[d] = xr[d] + o;
  }
  float mu = 0.f;
  #pragma unroll
  for (int d = 0; d < 16; d++) mu += h[d];
  mu *= (1.f / 16.f);
  float var = 0.f;
  #pragma unroll
  for (int d = 0; d < 16; d++) { float dd = h[d] - mu; var += dd * dd; }
  var *= (1.f / 16.f);
  float inv = 1.f / sqrtf(var + 1e-5f);
  float x1[16];
  #pragma unroll
  for (int d = 0; d < 16; d++) x1[d] = (h[d] - mu) * inv * sg1[d] + sbb1[d];
  float t1[32];
  #pragma unroll
  for (int j = 0; j < 32; j++) {
    float u = sb1[j];
    #pragma unroll
    for (int d = 0; d < 16; d++) u += x1[d] * sw1[j * 16 + d];
    t1[j] = fmaxf(u, 0.f);
  }
  float h2[16];
  #pragma unroll
  for (int d = 0; d < 16; d++) {
    float u = sb2[d];
    #pragma unroll
    for (int j = 0; j < 32; j++) u += t1[j] * sw2[d * 32 + j];
    h2[d] = x1[d] + u;
  }
  mu = 0.f;
  #pragma unroll
  for (int d = 0; d < 16; d++) mu += h2[d];
  mu *= (1.f / 16.f);
  var = 0.f;
  #pragma unroll
  for (int d = 0; d < 16; d++) { float dd = h2[d] - mu; var += dd * dd; }
  var *= (1.f / 16.f);
  inv = 1.f / sqrtf(var + 1e-5f);
  float pv = 0.f;
  #pragma unroll
  for (int d = 0; d < 16; d++)
    pv += ((h2[d] - mu) * inv * sg2[d] + sbb2[d]) * swf[d];
  double part = waveReduceSum((double)pv);
  __shared__ double red[4];
  int wid = tid >> 6, lane = tid & 63;
  if (lane == 0) red[wid] = part;
  __syncthreads();
  if (tid == 0) {
    double S = red[0] + red[1] + red[2] + red[3];
    float add = (float)(S / 1280.0);
    if (blockIdx.x % 5 == 0) add += bfc[0];
    atomicAdd(&out[bb], add);
  }
}

// ---------------- launch ------------------------------------------------------
extern "C" void kernel_launch(void* const* d_in, const int* in_sizes, int n_in,
                              void* d_out, int out_size, void* d_ws, size_t ws_size,
                              hipStream_t stream) {
  const float* x    = (const float*)d_in[0];
  const float* cw   = (const float*)d_in[1];
  const float* cb   = (const float*)d_in[2];
  const float* g0   = (const float*)d_in[3];
  const float* bt0  = (const float*)d_in[4];
  const float* wqkv = (const float*)d_in[5];
  const float* bqkv = (const float*)d_in[6];
  const float* wo   = (const float*)d_in[7];
  const float* bo   = (const float*)d_in[8];
  const float* w1   = (const float*)d_in[9];
  const float* b1   = (const float*)d_in[10];
  const float* w2   = (const float*)d_in[11];
  const float* b2   = (const float*)d_in[12];
  const float* g1   = (const float*)d_in[13];
  const float* bb1  = (const float*)d_in[14];
  const float* g2   = (const float*)d_in[15];
  const float* bb2  = (const float*)d_in[16];
  const float* wfc  = (const float*)d_in[17];
  const float* bfc  = (const float*)d_in[18];
  float* out = (float*)d_out;

  float* ws = (float*)d_ws;
  float* xs = ws;                       // 640*2000 = 1,280,000 (filtered in-place;
                                        // dead after k_resample_norm -> reused as A)
  float* y1 = xs + 1280000;             // spacer (dead)
  float* xn = y1 + 1306880;             // 640*1280   =   819,200
  float* x0 = xn + 819200;              // 64*1280*16 = 1,310,720
  float* Q  = x0 + 1310720;
  float* Kb = Q  + 1310720;
  float* Vb = Kb + 1310720;
  float* pe = Vb + 1310720;             // 1280*16 = 20,480  (total ~36 MB)
  float* Abuf = ws;                     // attention output (reuses dead xs)

  FiltArg fc; CorArg co; FirArg fa;
  build_filt(fc, co);
  design_fir(fa);

  k_chansel_pe<<<580, 256, 0, stream>>>(x, xs, pe, out);
  k_filtfilt<<<640, 64, 0, stream>>>(xs, fc, co);
  k_resample_norm<<<640, 256, 0, stream>>>(xs, xn, fa);
  k_conv_ln_pe_qkv<<<320, 256, 0, stream>>>(xn, cw, cb, g0, bt0, wqkv, bqkv,
                                            pe, x0, Q, Kb, Vb);
  k_attn_mfma<<<1280, 256, 0, stream>>>(Q, Kb, Vb, Abuf);
  k_combine_pool<<<320, 256, 0, stream>>>(Abuf, x0, wo, bo, w1, b1, w2, b2,
                                          g1, bb1, g2, bb2, wfc, bfc, out);
}